// Round 7
// baseline (1060.914 us; speedup 1.0000x reference)
//
#include <hip/hip_runtime.h>

// GlobalDistNet forward, round 14:
//  - Channel-split aggregations v3: pass derived from BLOCK PARITY (pass=bx&1).
//    Consecutive blockIdx round-robin across the 8 XCDs => even blocks on XCDs
//    {0,2,4,6} handle channel-half 0, odd blocks on {1,3,5,7} handle half 1.
//    Each XCD's 4MB L2 then only sees a 4.9MB footprint (82% hit vs 41%).
//    r13's pass=bx>=nwb had no XCD affinity -> both halves on every XCD -> no gain.
//  - Wave processes 2 edges/round (lanes 0-31 / 32-63), 4B per lane: transaction
//    shape identical to unsplit kernel; __shfl_xor(.,32) merges partials.
//  - Keeps r12 wins: stats fused into k_mfma_lin prologue (1 k_stats left),
//    residual fusion, 8-round gather ILP, r9 embed body (half-major H write).

typedef _Float16 f16;
typedef f16 f16x8 __attribute__((ext_vector_type(8)));
typedef f16 f16x4 __attribute__((ext_vector_type(4)));
typedef f16 f16x2 __attribute__((ext_vector_type(2)));
typedef float f32x4 __attribute__((ext_vector_type(4)));

__device__ __forceinline__ float lrelu(float x, float s){ return x>=0.f? x : s*x; }

// ---------------- CSR build ----------------
__global__ __launch_bounds__(256) void k_deg(const int* __restrict__ dst,
                                             int* __restrict__ deg, int E) {
  int i = blockIdx.x * 256 + threadIdx.x;
  if (i < E) atomicAdd(&deg[dst[i]], 1);
}

__global__ __launch_bounds__(1024) void k_scan1(const int* __restrict__ deg,
    int* __restrict__ row_ptr, int* __restrict__ bsum, float* __restrict__ dinv, int n) {
  int b = blockIdx.x, t = threadIdx.x, i = b * 1024 + t;
  __shared__ int sd[1024];
  int v = (i < n) ? deg[i] : 0;
  if (i < n) dinv[i] = rsqrtf((float)(v + 1));   // +1 self loop
  sd[t] = v;
  __syncthreads();
  for (int off = 1; off < 1024; off <<= 1) {
    int o = (t >= off) ? sd[t - off] : 0;
    __syncthreads();
    sd[t] += o;
    __syncthreads();
  }
  if (i < n) row_ptr[i + 1] = sd[t];
  if (t == 1023) bsum[b] = sd[1023];
  if (b == 0 && t == 0) row_ptr[0] = 0;
}

__global__ __launch_bounds__(64) void k_scan2(int* __restrict__ bsum, int nb) {
  int lane = threadIdx.x;
  int v = (lane < nb) ? bsum[lane] : 0;
  int x = v;
  for (int off = 1; off < 64; off <<= 1) {
    int o = __shfl_up(x, off, 64);
    if (lane >= off) x += o;
  }
  if (lane < nb) bsum[lane] = x - v;
}

__global__ __launch_bounds__(256) void k_scan3(int* __restrict__ row_ptr,
                                               const int* __restrict__ bsum, int n) {
  int i = blockIdx.x * 256 + threadIdx.x;
  if (i < n) row_ptr[i + 1] += bsum[i >> 10];
}

__global__ __launch_bounds__(256) void k_fill(const int* __restrict__ src,
                                              const int* __restrict__ dst,
                                              const int* __restrict__ row_ptr,
                                              const float* __restrict__ dinv,
                                              int* __restrict__ fill,
                                              int* __restrict__ csr,
                                              float* __restrict__ csrw, int E) {
  int i = blockIdx.x * 256 + threadIdx.x;
  if (i < E) {
    int d = dst[i], s = src[i];
    int pos = row_ptr[d] + atomicAdd(&fill[d], 1);
    csr[pos] = s;
    csrw[pos] = dinv[d] * dinv[s];
  }
}

// ---------------- conversions / packing ----------------
__global__ __launch_bounds__(256) void k_conv_emb(const float* __restrict__ src,
                                                  f16* __restrict__ dst, int total4) {
  int i = blockIdx.x * 256 + threadIdx.x;
  if (i >= total4) return;
  float4 v = ((const float4*)src)[i];
  f16x4 o = { (f16)v.x, (f16)v.y, (f16)v.z, (f16)v.w };
  ((f16x4*)dst)[i] = o;
}

__global__ __launch_bounds__(256) void k_pack_w(const float* __restrict__ W,
    f16* __restrict__ hi, int kb_total) {
  int idx = blockIdx.x * 256 + threadIdx.x;
  int c = idx & 127, kb = idx >> 7;
  if (kb >= kb_total) return;
  f16x8 hv;
#pragma unroll
  for (int j = 0; j < 8; j++) hv[j] = (f16)W[(size_t)(kb*8 + j) * 128 + c];
  ((f16x8*)hi)[idx] = hv;
}

__global__ __launch_bounds__(256) void k_pack_w8(const float* __restrict__ gcnW,
    const float* __restrict__ gatW, f16* __restrict__ hi, f16* __restrict__ lo) {
  int mat = blockIdx.y;
  const float* W = (mat < 4) ? gcnW + (size_t)mat * 16384 : gatW + (size_t)(mat - 4) * 16384;
  int idx = blockIdx.x * 256 + threadIdx.x;
  int c = idx & 127, kb = idx >> 7;
  f16x8 hv, lv;
#pragma unroll
  for (int j = 0; j < 8; j++) {
    float v = W[(size_t)(kb*8 + j) * 128 + c];
    f16 h = (f16)v;
    hv[j] = h; lv[j] = (f16)(v - (float)h);
  }
  ((f16x8*)hi)[mat * 2048 + idx] = hv;
  ((f16x8*)lo)[mat * 2048 + idx] = lv;
}

// ---------------- MFMA GEMM: embed-gather A, K=4128, dual K-half block ------------
#define APAD 152
__global__ __launch_bounds__(512) void k_mfma_embed(const int* __restrict__ poi,
    const float* __restrict__ dist, const f16* __restrict__ eh,
    const f16* __restrict__ wh, f16* __restrict__ H16, int n) {
  __shared__ __attribute__((aligned(16))) char smem[49152];
  int* poi_s = (int*)smem;
  f16* aS    = (f16*)(smem + 8192);
  f16* OT    = (f16*)smem;
  float* F   = (float*)(smem + 16384);
  int tid = threadIdx.x;
  int bn = blockIdx.x * 64;
  int half = tid >> 8;
  int t2 = tid & 255;
  int ln = t2 >> 2, qt = t2 & 3;
  int xrow = bn + ln; if (xrow > n - 1) xrow = n - 1;
  {
#pragma unroll
    for (int jj = 0; jj < 4; jj++)
      poi_s[half * 1024 + (qt * 4 + jj) * 64 + ln] =
        poi[(size_t)xrow * 32 + half * 16 + qt * 4 + jj];
  }
  int w2 = (tid >> 6) & 3, lane = tid & 63;
  int q = lane >> 4, l15 = lane & 15;
  int mtb = (w2 & 1) * 2;
  int ntb = (w2 >> 1) * 4;
  f16* aH = aS + half * 64 * APAD;
  f32x4 acc[2][4];
#pragma unroll
  for (int a = 0; a < 2; a++)
#pragma unroll
    for (int b = 0; b < 4; b++) { acc[a][b][0]=0.f; acc[a][b][1]=0.f; acc[a][b][2]=0.f; acc[a][b][3]=0.f; }
  __syncthreads();

  f16x8 r0, r1, r2, r3;
  {
    const f16* srcp = eh + (size_t)poi_s[half * 1024 + ln] * 128 + qt * 32;
    r0 = *(const f16x8*)(srcp);      r1 = *(const f16x8*)(srcp + 8);
    r2 = *(const f16x8*)(srcp + 16); r3 = *(const f16x8*)(srcp + 24);
  }

#pragma unroll 1
  for (int j = 0; j < 16; j++) {
    __syncthreads();
    f16* wp = aH + ln * APAD + qt * 32;
    *(f16x8*)(wp) = r0; *(f16x8*)(wp + 8) = r1;
    *(f16x8*)(wp + 16) = r2; *(f16x8*)(wp + 24) = r3;
    if (j + 1 < 16) {
      const f16* srcp = eh + (size_t)poi_s[half * 1024 + (j + 1) * 64 + ln] * 128 + qt * 32;
      r0 = *(const f16x8*)(srcp);      r1 = *(const f16x8*)(srcp + 8);
      r2 = *(const f16x8*)(srcp + 16); r3 = *(const f16x8*)(srcp + 24);
    }
    __syncthreads();
#pragma unroll
    for (int kcl = 0; kcl < 4; kcl++) {
      f16x8 a_h[2];
#pragma unroll
      for (int mi = 0; mi < 2; mi++)
        a_h[mi] = *(const f16x8*)(aH + ((mtb + mi) * 16 + l15) * APAD + kcl * 32 + q * 8);
      int kb = (half * 16 + j) * 16 + kcl * 4 + q;
#pragma unroll
      for (int ni = 0; ni < 4; ni++) {
        f16x8 bh = *(const f16x8*)(wh + ((size_t)kb * 128 + (ntb + ni) * 16 + l15) * 8);
#pragma unroll
        for (int mi = 0; mi < 2; mi++)
          acc[mi][ni] = __builtin_amdgcn_mfma_f32_16x16x32_f16(a_h[mi], bh, acc[mi][ni], 0, 0, 0);
      }
    }
  }
  if (half) {
    int nc0 = bn + (mtb + 0) * 16 + l15; if (nc0 > n - 1) nc0 = n - 1;
    int nc1 = bn + (mtb + 1) * 16 + l15; if (nc1 > n - 1) nc1 = n - 1;
    f16x8 ad[2];
#pragma unroll
    for (int mi = 0; mi < 2; mi++) {
      int nc = mi ? nc1 : nc0;
      const float* dp = dist + (size_t)nc * 32 + q * 8;
      float4 d0 = *(const float4*)dp, d1 = *(const float4*)(dp + 4);
      ad[mi][0]=(f16)d0.x; ad[mi][1]=(f16)d0.y; ad[mi][2]=(f16)d0.z; ad[mi][3]=(f16)d0.w;
      ad[mi][4]=(f16)d1.x; ad[mi][5]=(f16)d1.y; ad[mi][6]=(f16)d1.z; ad[mi][7]=(f16)d1.w;
    }
    int kb = 512 + q;
#pragma unroll
    for (int ni = 0; ni < 4; ni++) {
      f16x8 bh = *(const f16x8*)(wh + ((size_t)kb * 128 + (ntb + ni) * 16 + l15) * 8);
#pragma unroll
      for (int mi = 0; mi < 2; mi++)
        acc[mi][ni] = __builtin_amdgcn_mfma_f32_16x16x32_f16(ad[mi], bh, acc[mi][ni], 0, 0, 0);
    }
  }
  __syncthreads();
  if (half) {
#pragma unroll
    for (int mi = 0; mi < 2; mi++)
#pragma unroll
      for (int ni = 0; ni < 4; ni++)
#pragma unroll
        for (int r = 0; r < 4; r++)
          F[((mtb + mi) * 16 + q * 4 + r) * 128 + (ntb + ni) * 16 + l15] = acc[mi][ni][r];
  }
  __syncthreads();
  if (!half) {
#pragma unroll
    for (int mi = 0; mi < 2; mi++)
#pragma unroll
      for (int ni = 0; ni < 4; ni++)
#pragma unroll
        for (int r = 0; r < 4; r++) {
          int o = ((mtb + mi) * 16 + q * 4 + r) * 128 + (ntb + ni) * 16 + l15;
          OT[o] = (f16)(acc[mi][ni][r] + F[o]);
        }
  }
  __syncthreads();
  // H16 half-major [2][N][64]
#pragma unroll
  for (int ch = 0; ch < 2; ch++) {
    int c1024 = tid + ch * 512;
    int row = c1024 >> 4, c8 = c1024 & 15;
    if (bn + row < n) {
      f16* dstp = H16 + (size_t)(c8 >> 3) * ((size_t)n * 64) + (size_t)(bn + row) * 64 + (c8 & 7) * 8;
      *(f16x8*)dstp = *(const f16x8*)(OT + row * 128 + c8 * 8);
    }
  }
}

// ---------------- MFMA GEMM: K=128; fused in-block stats + residual + a-dot -----
#define LPAD 136
__global__ __launch_bounds__(256) void k_mfma_lin(const f16* __restrict__ XH,
    const f16* __restrict__ wh, const f16* __restrict__ wl,
    f16* __restrict__ H16, int n,
    const float* __restrict__ asrc, const float* __restrict__ adst,
    float* __restrict__ als, float* __restrict__ ald,
    const float* __restrict__ yres, const float* __restrict__ ps,
    const float* __restrict__ pq, const float* __restrict__ nw,
    const float* __restrict__ nbb, const float* __restrict__ nms,
    float* __restrict__ xf) {
  __shared__ __attribute__((aligned(16))) char smem[64 * LPAD * 2 + 3072];
  f16* aS = (f16*)smem;
  f16* ot = (f16*)smem;
  float* dsrc = (float*)(smem + 16384);
  float* ddst = (float*)(smem + 16896);
  float* scf  = (float*)(smem + 17408);   // [128] scale
  float* shf  = scf + 128;                // [128] shift
  float* sst1 = (float*)(smem + 18432);   // [256]
  float* sst2 = sst1 + 256;               // [256]
  int tid = threadIdx.x;
  int bn = blockIdx.x * 64;
  int ln = tid >> 2, qt = tid & 3;
  int w = tid >> 6, lane = tid & 63;
  int q = lane >> 4, l15 = lane & 15;
  int mtb = (w & 1) * 2;
  int ntb = (w >> 1) * 4;
  f16* wp = aS + ln * LPAD + qt * 32;
  if (yres) {
    // in-block GraphNorm stats from psum partials (visible via launch boundary)
    {
      int c = tid & 127, hf = tid >> 7;
      float S = 0.f, Q = 0.f;
      for (int s = hf; s < 128; s += 2) { S += ps[s * 128 + c]; Q += pq[s * 128 + c]; }
      sst1[tid] = S; sst2[tid] = Q;
      __syncthreads();
      if (hf == 0) {
        double Sd = (double)sst1[c] + (double)sst1[c + 128];
        double Qd = (double)sst2[c] + (double)sst2[c + 128];
        double invn = 1.0 / (double)n;
        double mean = Sd * invn;
        double mt = (double)nms[c] * mean;
        double var = Qd * invn - 2.0 * mt * mean + mt * mt;
        float rstd = rsqrtf((float)var + 1e-5f);
        float sc = nw[c] * rstd;
        scf[c] = sc;
        shf[c] = nbb[c] - sc * (float)mt;
      }
      __syncthreads();
    }
    // fused residual: x += lrelu(scale*y + shift); LDS gets f16(x)
    int row = bn + ln;
    if (row < n) {
      const float4* yp = (const float4*)(yres + (size_t)row * 128 + qt * 32);
      float4* xp = (float4*)(xf + (size_t)row * 128 + qt * 32);
      const float4* scp = (const float4*)(scf + qt * 32);
      const float4* shp = (const float4*)(shf + qt * 32);
#pragma unroll
      for (int jj = 0; jj < 8; jj++) {
        float4 yv = yp[jj], xv = xp[jj], sc = scp[jj], sh = shp[jj];
        xv.x += lrelu(sc.x * yv.x + sh.x, 0.01f);
        xv.y += lrelu(sc.y * yv.y + sh.y, 0.01f);
        xv.z += lrelu(sc.z * yv.z + sh.z, 0.01f);
        xv.w += lrelu(sc.w * yv.w + sh.w, 0.01f);
        xp[jj] = xv;
        f16x4 o = { (f16)xv.x, (f16)xv.y, (f16)xv.z, (f16)xv.w };
        *(f16x4*)(wp + jj * 4) = o;
      }
    } else {
      f16x8 z = {};
#pragma unroll
      for (int jj = 0; jj < 4; jj++) *(f16x8*)(wp + jj * 8) = z;
    }
  } else {
    int xrow = bn + ln; if (xrow > n - 1) xrow = n - 1;
    const f16* srcp = XH + (size_t)xrow * 128 + qt * 32;
    *(f16x8*)(wp)      = *(const f16x8*)(srcp);
    *(f16x8*)(wp + 8)  = *(const f16x8*)(srcp + 8);
    *(f16x8*)(wp + 16) = *(const f16x8*)(srcp + 16);
    *(f16x8*)(wp + 24) = *(const f16x8*)(srcp + 24);
  }
  float av[4], bv[4];
  if (asrc) {
#pragma unroll
    for (int ni = 0; ni < 4; ni++) {
      av[ni] = asrc[(ntb + ni) * 16 + l15];
      bv[ni] = adst[(ntb + ni) * 16 + l15];
    }
  }
  f32x4 acc[2][4];
#pragma unroll
  for (int a = 0; a < 2; a++)
#pragma unroll
    for (int b = 0; b < 4; b++) { acc[a][b][0]=0.f; acc[a][b][1]=0.f; acc[a][b][2]=0.f; acc[a][b][3]=0.f; }
  __syncthreads();
#pragma unroll
  for (int kcl = 0; kcl < 4; kcl++) {
    f16x8 a_h[2];
#pragma unroll
    for (int mi = 0; mi < 2; mi++)
      a_h[mi] = *(const f16x8*)(aS + ((mtb + mi) * 16 + l15) * LPAD + kcl * 32 + q * 8);
    int kb = kcl * 4 + q;
#pragma unroll
    for (int ni = 0; ni < 4; ni++) {
      size_t boff = ((size_t)kb * 128 + (ntb + ni) * 16 + l15) * 8;
      f16x8 bh = *(const f16x8*)(wh + boff);
      f16x8 bl = *(const f16x8*)(wl + boff);
#pragma unroll
      for (int mi = 0; mi < 2; mi++) {
        acc[mi][ni] = __builtin_amdgcn_mfma_f32_16x16x32_f16(a_h[mi], bh, acc[mi][ni], 0, 0, 0);
        acc[mi][ni] = __builtin_amdgcn_mfma_f32_16x16x32_f16(a_h[mi], bl, acc[mi][ni], 0, 0, 0);
      }
    }
  }
  __syncthreads();
  if (asrc) {
#pragma unroll
    for (int mi = 0; mi < 2; mi++)
#pragma unroll
      for (int r = 0; r < 4; r++) {
        float ps2 = 0.f, pd = 0.f;
#pragma unroll
        for (int ni = 0; ni < 4; ni++) { ps2 += acc[mi][ni][r] * av[ni]; pd += acc[mi][ni][r] * bv[ni]; }
#pragma unroll
        for (int msk = 8; msk > 0; msk >>= 1) {
          ps2 += __shfl_xor(ps2, msk, 64);
          pd += __shfl_xor(pd, msk, 64);
        }
        if (l15 == 0) {
          int row = (mtb + mi) * 16 + q * 4 + r;
          dsrc[row * 2 + (w >> 1)] = ps2;
          ddst[row * 2 + (w >> 1)] = pd;
        }
      }
  }
#pragma unroll
  for (int mi = 0; mi < 2; mi++)
#pragma unroll
    for (int ni = 0; ni < 4; ni++)
#pragma unroll
      for (int r = 0; r < 4; r++)
        ot[((mtb + mi) * 16 + q * 4 + r) * 128 + (ntb + ni) * 16 + l15] = (f16)acc[mi][ni][r];
  __syncthreads();
  if (bn + ln < n) {
    // H16 half-major [2][N][64]
    const f16* srcp = ot + ln * 128 + qt * 32;
    f16* dstp = H16 + (size_t)(qt >> 1) * ((size_t)n * 64) + (size_t)(bn + ln) * 64 + (qt & 1) * 32;
#pragma unroll
    for (int jj = 0; jj < 4; jj++)
      *(f16x8*)(dstp + jj * 8) = *(const f16x8*)(srcp + jj * 8);
  }
  if (asrc && tid < 64 && bn + tid < n) {
    als[bn + tid] = dsrc[tid * 2] + dsrc[tid * 2 + 1];
    ald[bn + tid] = ddst[tid * 2] + ddst[tid * 2 + 1];
  }
}

// ---------------- GCN aggregation: XCD-parity passes, 2 edges/round, 4B lanes ---
__global__ __launch_bounds__(256) void k_gcn_agg16(const f16* __restrict__ H,
    const float* __restrict__ dinv, const int* __restrict__ row_ptr,
    const int* __restrict__ csr, const float* __restrict__ csrw,
    const float* __restrict__ bias,
    float* __restrict__ yout, f16* __restrict__ xh_out, int n, int nwb,
    int leaky_flag, float* __restrict__ psum, float* __restrict__ psumsq) {
  int w = threadIdx.x >> 6;
  int bx = blockIdx.x;
  int pass = bx & 1;                 // block parity ~ XCD parity: per-XCD L2 sees one half
  int node = (bx >> 1) * 4 + w;
  int lane = threadIdx.x & 63;
  int l5 = lane >> 5, m = lane & 31;
  const f16x2* Hh2 = (const f16x2*)(H + (size_t)pass * ((size_t)n * 64));
  __shared__ float s1[4][64], s2[4][64];
  float vx = 0.f, vy = 0.f;
  if (node < n) {
    int rs = row_ptr[node], re = row_ptr[node + 1];
    int d = re - rs;
    float dn = dinv[node];
    int  sidx = (lane < d) ? csr[rs + lane]  : 0;
    float swt = (lane < d) ? csrw[rs + lane] : 0.f;
    f16x2 sv = Hh2[(size_t)node * 32 + m];
    float selfw = l5 ? 0.f : dn * dn;           // self term counted once (half 0)
    float ax = selfw * (float)sv[0], ay = selfw * (float)sv[1];
    int dl = d < 64 ? d : 64;
    int rounds = (dl + 1) >> 1;
    int r8v = (rounds + 7) & ~7;   // <=32; edge idx 2*(r+u)+l5 <= 63, pad weight 0
    for (int r = 0; r < r8v; r += 8) {
      int ii[8]; float ww[8];
#pragma unroll
      for (int u = 0; u < 8; u++) {
        int src = 2 * (r + u) + l5;
        ii[u] = __shfl(sidx, src, 64);
        ww[u] = __shfl(swt,  src, 64);
      }
      f16x2 vv[8];
#pragma unroll
      for (int u = 0; u < 8; u++) vv[u] = Hh2[(size_t)ii[u] * 32 + m];
#pragma unroll
      for (int u = 0; u < 8; u++) {
        ax += ww[u] * (float)vv[u][0];
        ay += ww[u] * (float)vv[u][1];
      }
    }
    for (int e = rs + 64; e < re; e += 2) {   // rare deg>64 tail (paired)
      int ee = e + l5;
      int s = (ee < re) ? csr[ee] : 0;
      float wv = (ee < re) ? csrw[ee] : 0.f;
      f16x2 v = Hh2[(size_t)s * 32 + m];
      ax += wv * (float)v[0]; ay += wv * (float)v[1];
    }
    ax += __shfl_xor(ax, 32, 64);
    ay += __shfl_xor(ay, 32, 64);
    float2 bvv = ((const float2*)(bias + pass * 64))[m];
    vx = ax + bvv.x; vy = ay + bvv.y;
    if (leaky_flag) { vx = lrelu(vx, 0.01f); vy = lrelu(vy, 0.01f); }
    if (l5 == 0) {
      ((float2*)(yout + (size_t)node * 128 + pass * 64))[m] = make_float2(vx, vy);
      if (xh_out) {
        f16x2 o = { (f16)vx, (f16)vy };
        ((f16x2*)xh_out)[(size_t)node * 64 + pass * 32 + m] = o;
      }
    }
  }
  if (psum) {
    if (l5 == 0) {
      s1[w][2*m] = vx;  s1[w][2*m+1] = vy;
      s2[w][2*m] = vx*vx; s2[w][2*m+1] = vy*vy;
    }
    __syncthreads();
    int t = threadIdx.x;
    if (t < 64) {
      float S = s1[0][t] + s1[1][t] + s1[2][t] + s1[3][t];
      float Q = s2[0][t] + s2[1][t] + s2[2][t] + s2[3][t];
      int slot = bx & 127;
      atomicAdd(&psum[slot * 128 + pass * 64 + t], S);
      atomicAdd(&psumsq[slot * 128 + pass * 64 + t], Q);
    }
  }
}

// ---------------- GAT aggregation: XCD-parity passes, 2 edges/round, 4B lanes ---
__global__ __launch_bounds__(256) void k_gat_agg16(const f16* __restrict__ H,
    const float* __restrict__ als, const float* __restrict__ ald,
    const int* __restrict__ row_ptr, const int* __restrict__ csr,
    const float* __restrict__ bias, float* __restrict__ yout, int n, int nwb,
    float* __restrict__ psum, float* __restrict__ psumsq) {
  int w = threadIdx.x >> 6;
  int bx = blockIdx.x;
  int pass = bx & 1;                 // block parity ~ XCD parity
  int node = (bx >> 1) * 4 + w;
  int lane = threadIdx.x & 63;
  int l5 = lane >> 5, m = lane & 31;
  const f16x2* Hh2 = (const f16x2*)(H + (size_t)pass * ((size_t)n * 64));
  __shared__ float s1[4][64], s2[4][64];
  float vx = 0.f, vy = 0.f;
  if (node < n) {
    int rs = row_ptr[node], re = row_ptr[node + 1];
    int d = re - rs;
    float aldn = ald[node];
    float e_self = lrelu(als[node] + aldn, 0.2f);
    f16x2 sv = Hh2[(size_t)node * 32 + m];
    float ax, ay, sm;
    if (d <= 64) {
      int sidx = (lane < d) ? csr[rs + lane] : 0;
      float e_k = (lane < d) ? lrelu(als[sidx] + aldn, 0.2f) : -3.4e38f;
      float tmx = e_k;
      for (int off = 1; off < 64; off <<= 1) tmx = fmaxf(tmx, __shfl_xor(tmx, off, 64));
      float mx = fmaxf(e_self, tmx);
      float g_k = (lane < d) ? __expf(e_k - mx) : 0.f;   // pad lanes weight 0
      float tsm = g_k;
      for (int off = 1; off < 64; off <<= 1) tsm += __shfl_xor(tsm, off, 64);
      float ws = __expf(e_self - mx);
      sm = tsm + ws;
      float selfw = l5 ? 0.f : ws;
      ax = selfw * (float)sv[0]; ay = selfw * (float)sv[1];
      int rounds = (d + 1) >> 1;
      int r8v = (rounds + 7) & ~7;
      for (int r = 0; r < r8v; r += 8) {
        int ii[8]; float gg[8];
#pragma unroll
        for (int u = 0; u < 8; u++) {
          int src = 2 * (r + u) + l5;
          ii[u] = __shfl(sidx, src, 64);
          gg[u] = __shfl(g_k,  src, 64);
        }
        f16x2 vv[8];
#pragma unroll
        for (int u = 0; u < 8; u++) vv[u] = Hh2[(size_t)ii[u] * 32 + m];
#pragma unroll
        for (int u = 0; u < 8; u++) {
          ax += gg[u] * (float)vv[u][0];
          ay += gg[u] * (float)vv[u][1];
        }
      }
    } else {  // rare deg>64 slow path (paired serial)
      float mx = e_self;
      for (int i = rs + lane; i < re; i += 64) mx = fmaxf(mx, lrelu(als[csr[i]] + aldn, 0.2f));
      for (int off = 1; off < 64; off <<= 1) mx = fmaxf(mx, __shfl_xor(mx, off, 64));
      float ws = __expf(e_self - mx);
      float selfw = l5 ? 0.f : ws;
      ax = selfw * (float)sv[0]; ay = selfw * (float)sv[1];
      float smA = 0.f;
      for (int e = rs; e < re; e += 2) {
        int ee = e + l5;
        int s = (ee < re) ? csr[ee] : 0;
        float g = (ee < re) ? __expf(lrelu(als[s] + aldn, 0.2f) - mx) : 0.f;
        f16x2 v = Hh2[(size_t)s * 32 + m];
        smA += g; ax += g * (float)v[0]; ay += g * (float)v[1];
      }
      smA += __shfl_xor(smA, 32, 64);   // g uniform within half; cross-sum totals
      sm = ws + smA;
    }
    ax += __shfl_xor(ax, 32, 64);
    ay += __shfl_xor(ay, 32, 64);
    float inv_s = 1.f / sm;
    float2 bvv = ((const float2*)(bias + pass * 64))[m];
    vx = ax * inv_s + bvv.x; vy = ay * inv_s + bvv.y;
    if (l5 == 0)
      ((float2*)(yout + (size_t)node * 128 + pass * 64))[m] = make_float2(vx, vy);
  }
  if (l5 == 0) {
    s1[w][2*m] = vx;  s1[w][2*m+1] = vy;
    s2[w][2*m] = vx*vx; s2[w][2*m+1] = vy*vy;
  }
  __syncthreads();
  int t = threadIdx.x;
  if (t < 64) {
    float S = s1[0][t] + s1[1][t] + s1[2][t] + s1[3][t];
    float Q = s2[0][t] + s2[1][t] + s2[2][t] + s2[3][t];
    int slot = bx & 127;
    atomicAdd(&psum[slot * 128 + pass * 64 + t], S);
    atomicAdd(&psumsq[slot * 128 + pass * 64 + t], Q);
  }
}

// ---------------- GraphNorm stats (single use: final GAT stats for head) -------
__global__ __launch_bounds__(256) void k_stats(const float* __restrict__ psum,
    const float* __restrict__ psumsq, const float* __restrict__ w,
    const float* __restrict__ bb, const float* __restrict__ ms,
    float* __restrict__ scaleA, float* __restrict__ shiftA, int n) {
  int t = threadIdx.x, c = t & 127, half = t >> 7;
  float S = 0.f, Q = 0.f;
  for (int s = half; s < 128; s += 2) { S += psum[s * 128 + c]; Q += psumsq[s * 128 + c]; }
  __shared__ float sh[256], sq[256];
  sh[t] = S; sq[t] = Q;
  __syncthreads();
  if (half == 0) {
    double Sd = (double)sh[c] + (double)sh[c + 128];
    double Qd = (double)sq[c] + (double)sq[c + 128];
    double invn = 1.0 / (double)n;
    double mean = Sd * invn;
    double mt = (double)ms[c] * mean;
    double var = Qd * invn - 2.0 * mt * mean + mt * mt;
    float rstd = rsqrtf((float)var + 1e-5f);
    float sc = w[c] * rstd;
    scaleA[c] = sc;
    shiftA[c] = bb[c] - sc * (float)mt;
  }
}

// ---------------- Output head: final residual fused into the W_out dot -------
__global__ __launch_bounds__(256) void k_dot1_res(const float* __restrict__ y,
    const float* __restrict__ scA, const float* __restrict__ shA,
    const float* __restrict__ x, const float* __restrict__ wv,
    float* __restrict__ o, int n) {
  int node = blockIdx.x * 4 + (threadIdx.x >> 6);
  int lane = threadIdx.x & 63;
  if (node >= n) return;
  float2 yv = ((const float2*)y)[(size_t)node * 64 + lane];
  float2 xv = ((const float2*)x)[(size_t)node * 64 + lane];
  float2 sc = ((const float2*)scA)[lane];
  float2 sh = ((const float2*)shA)[lane];
  float hx = xv.x + lrelu(sc.x * yv.x + sh.x, 0.01f);
  float hy = xv.y + lrelu(sc.y * yv.y + sh.y, 0.01f);
  float2 v1 = ((const float2*)wv)[lane];
  float s1 = hx * v1.x + hy * v1.y;
  for (int off = 32; off > 0; off >>= 1) s1 += __shfl_down(s1, off, 64);
  if (lane == 0) o[node] = s1;
}

__global__ __launch_bounds__(256) void k_scalar_agg(const float* __restrict__ xsv,
    const float* __restrict__ dinv, const int* __restrict__ row_ptr,
    const int* __restrict__ csr, const float* __restrict__ csrw,
    const float* __restrict__ b_out, float* __restrict__ xout, int n) {
  int i = blockIdx.x * 256 + threadIdx.x;
  if (i >= n) return;
  float dn = dinv[i];
  float acc = dn * dn * xsv[i];
  int re = row_ptr[i + 1];
  for (int e = row_ptr[i]; e < re; e++)
    acc += csrw[e] * xsv[csr[e]];
  xout[i] = lrelu(acc + b_out[0], 0.01f);
}

__global__ __launch_bounds__(256) void k_fc1(const float* __restrict__ xout,
    const float* __restrict__ fw, float* __restrict__ pfc, int n, int chunk) {
  int b = blockIdx.x, t = threadIdx.x;
  int c = t & 127, half = t >> 7;
  int s0 = b * chunk;
  int s1 = s0 + chunk; if (s1 > n) s1 = n;
  float s = 0.f;
  for (int i = s0 + half; i < s1; i += 2) s += xout[i] * fw[(size_t)i * 128 + c];
  __shared__ float sh[256];
  sh[t] = s; __syncthreads();
  if (half == 0) pfc[b * 128 + c] = sh[c] + sh[c + 128];
}

__global__ __launch_bounds__(128) void k_final(const float* __restrict__ pfc,
    const float* __restrict__ b1, const float* __restrict__ fw2,
    const float* __restrict__ b2, float* __restrict__ out) {
  int c = threadIdx.x;
  float s = 0.f;
  for (int b = 0; b < 128; b++) s += pfc[b * 128 + c];
  float hv = lrelu(s + b1[c], 0.01f);
  __shared__ float h1[128];
  h1[c] = hv; __syncthreads();
  float o = b2[c];
  for (int j = 0; j < 128; j++) o += h1[j] * fw2[j * 128 + c];
  out[c] = o;
}

// ---------------- host ----------------
extern "C" void kernel_launch(void* const* d_in, const int* in_sizes, int n_in,
                              void* d_out, int out_size, void* d_ws, size_t ws_size,
                              hipStream_t stream) {
  const int* poi      = (const int*)d_in[0];
  const float* dist   = (const float*)d_in[1];
  const int* ei       = (const int*)d_in[2];
  const float* emb    = (const float*)d_in[3];
  const float* W_in   = (const float*)d_in[4];
  const float* b_in   = (const float*)d_in[5];
  const float* gcn_W  = (const float*)d_in[6];
  const float* gcn_b  = (const float*)d_in[7];
  const float* norm_w = (const float*)d_in[8];
  const float* norm_b = (const float*)d_in[9];
  const float* norm_ms= (const float*)d_in[10];
  const float* gat_W  = (const float*)d_in[11];
  const float* gat_as = (const float*)d_in[12];
  const float* gat_ad = (const float*)d_in[13];
  const float* gat_b  = (const float*)d_in[14];
  const float* W_out  = (const float*)d_in[15];
  const float* b_out  = (const float*)d_in[16];
  const float* fc1_W  = (const float*)d_in[17];
  const float* fc1_b  = (const float*)d_in[18];
  const float* fc2_W  = (const float*)d_in[19];
  const float* fc2_b  = (const float*)d_in[20];

  const int N   = in_sizes[0] / 32;
  const int E   = in_sizes[2] / 2;
  const int POI = in_sizes[3] / 128;
  const int* srcp = ei;
  const int* dstp = ei + E;
  float* out = (float*)d_out;

  char* p = (char*)d_ws;
  auto alloc = [&](size_t bytes) { char* r = p; p += (bytes + 255) & ~(size_t)255; return r; };
  float* x   = (float*)alloc((size_t)N * 128 * 4);
  f16* h16   = (f16*)alloc((size_t)N * 128 * 2);
  f16* xh    = (f16*)alloc((size_t)N * 128 * 2);
  size_t Rneed = (size_t)POI * 128 * 2;
  size_t Ry    = (size_t)N * 128 * 4;
  char* R = alloc(Rneed > Ry ? Rneed : Ry);
  f16* ehalf = (f16*)R;
  float* y   = (float*)R;
  const int KBIN = 4128 / 8;
  f16* wih = (f16*)alloc((size_t)KBIN * 128 * 8 * 2);
  f16* wsh = (f16*)alloc((size_t)8 * 16384 * 2);
  f16* wsl = (f16*)alloc((size_t)8 * 16384 * 2);
  float* dinv   = (float*)alloc((size_t)N * 4);
  float* als    = (float*)alloc((size_t)N * 4);
  float* ald    = (float*)alloc((size_t)N * 4);
  float* xsv    = (float*)alloc((size_t)N * 4);
  float* xout   = (float*)alloc((size_t)N * 4);
  float* statsbuf = (float*)alloc((size_t)32 * 16384 * 4);   // 2 MB
  float* pfc    = (float*)alloc(128 * 128 * 4);
  float* scaleA = (float*)alloc(128 * 4);
  float* shiftA = (float*)alloc(128 * 4);
  int* deg     = (int*)alloc((size_t)N * 2 * 4);
  int* fill    = deg + N;
  int* row_ptr = (int*)alloc(((size_t)N + 1) * 4);
  int* csr     = (int*)alloc((size_t)E * 4);
  float* csrw  = (float*)alloc((size_t)E * 4);
  int* bsum    = (int*)alloc(64 * 4);

  const int chunk = (N + 127) / 128;
  const int gblocks = (N + 63) / 64;
  const int eblocks = (E + 255) / 256;
  const int nwb = (N + 3) / 4;
  const int nb1024 = (N + 1023) / 1024;

  hipMemsetAsync(deg, 0, sizeof(int) * 2 * (size_t)N, stream);
  hipMemsetAsync(statsbuf, 0, (size_t)32 * 16384 * 4, stream);
  k_deg<<<eblocks, 256, 0, stream>>>(dstp, deg, E);
  k_scan1<<<nb1024, 1024, 0, stream>>>(deg, row_ptr, bsum, dinv, N);
  k_scan2<<<1, 64, 0, stream>>>(bsum, nb1024);
  k_scan3<<<(N + 255) / 256, 256, 0, stream>>>(row_ptr, bsum, N);
  k_fill<<<eblocks, 256, 0, stream>>>(srcp, dstp, row_ptr, dinv, fill, csr, csrw, E);

  int et4 = POI * 128 / 4;
  k_conv_emb<<<(et4 + 255) / 256, 256, 0, stream>>>(emb, ehalf, et4);
  k_pack_w<<<(KBIN * 128 + 255) / 256, 256, 0, stream>>>(W_in, wih, KBIN);
  k_pack_w8<<<dim3(8, 8), 256, 0, stream>>>(gcn_W, gat_W, wsh, wsl);

  // input layer
  k_mfma_embed<<<gblocks, 512, 0, stream>>>(poi, dist, ehalf, wih, h16, N);
  k_gcn_agg16<<<2 * nwb, 256, 0, stream>>>(h16, dinv, row_ptr, csr, csrw, b_in,
                                           x, xh, N, nwb, 1, nullptr, nullptr);

  for (int l = 0; l < 4; l++) {
    const f16* gh = wsh + (size_t)l * 16384;
    const f16* gl = wsl + (size_t)l * 16384;
    const f16* th = wsh + (size_t)(4 + l) * 16384;
    const f16* tl = wsl + (size_t)(4 + l) * 16384;
    float* ps0 = statsbuf + (size_t)(4 * l) * 16384;   // gcn psum (layer l)
    float* pq0 = ps0 + 16384;
    float* ps1 = ps0 + 2 * 16384;                      // gat psum (layer l)
    float* pq1 = ps0 + 3 * 16384;
    // GCN sub-unit: lin consumes previous-layer GAT stats (residual) for l>0
    if (l == 0)
      k_mfma_lin<<<gblocks, 256, 0, stream>>>(xh, gh, gl, h16, N,
          nullptr, nullptr, nullptr, nullptr,
          nullptr, nullptr, nullptr, nullptr, nullptr, nullptr, nullptr);
    else {
      float* ps1p = statsbuf + (size_t)(4 * (l - 1) + 2) * 16384;
      float* pq1p = ps1p + 16384;
      k_mfma_lin<<<gblocks, 256, 0, stream>>>(nullptr, gh, gl, h16, N,
          nullptr, nullptr, nullptr, nullptr,
          y, ps1p, pq1p, norm_w + (l - 1) * 128, norm_b + (l - 1) * 128,
          norm_ms + (l - 1) * 128, x);
    }
    k_gcn_agg16<<<2 * nwb, 256, 0, stream>>>(h16, dinv, row_ptr, csr, csrw,
                                             gcn_b + l * 128, y, (f16*)nullptr, N, nwb, 0,
                                             ps0, pq0);
    // GAT sub-unit: lin consumes this layer's GCN stats (residual); a-dot fused
    k_mfma_lin<<<gblocks, 256, 0, stream>>>(nullptr, th, tl, h16, N,
        gat_as + l * 128, gat_ad + l * 128, als, ald,
        y, ps0, pq0, norm_w + l * 128, norm_b + l * 128, norm_ms + l * 128, x);
    k_gat_agg16<<<2 * nwb, 256, 0, stream>>>(h16, als, ald, row_ptr, csr,
                                             gat_b + l * 128, y, N, nwb, ps1, pq1);
  }

  // output head: single k_stats for the final GAT norm, then fused dot
  {
    float* ps1 = statsbuf + (size_t)(4 * 3 + 2) * 16384;
    float* pq1 = ps1 + 16384;
    k_stats<<<1, 256, 0, stream>>>(ps1, pq1, norm_w + 3 * 128, norm_b + 3 * 128,
                                   norm_ms + 3 * 128, scaleA, shiftA, N);
  }
  k_dot1_res<<<nwb, 256, 0, stream>>>(y, scaleA, shiftA, x, W_out, xsv, N);
  k_scalar_agg<<<(N + 255) / 256, 256, 0, stream>>>(xsv, dinv, row_ptr, csr, csrw, b_out, xout, N);
  k_fc1<<<128, 256, 0, stream>>>(xout, fc1_W, pfc, N, chunk);
  k_final<<<1, 128, 0, stream>>>(pfc, fc1_b, fc2_W, fc2_b, out);
}

// Round 8
// 1008.396 us; speedup vs baseline: 1.0521x; 1.0521x over previous
//
#include <hip/hip_runtime.h>

// GlobalDistNet forward, round 15:
//  - REVERT r13/r14 channel-split aggs (two L2-capacity experiments both neutral:
//    aggs are random-256B fabric-service-rate bound, not miss-capacity bound).
//    Aggs/lin/H16 layout = r12 exactly (981 us best).
//  - Embed: LDS A-staging REMOVED. MFMA A-fragments loaded directly from eh
//    (16B per lane per kcl per mi; 8 independent loads/lane/iter), ZERO barriers
//    in the K-loop -> each wave is an independent load<->MFMA pipeline.
//    r10 lesson: deeper prefetch w/ barriers = VGPR cliff; this removes barriers.

typedef _Float16 f16;
typedef f16 f16x8 __attribute__((ext_vector_type(8)));
typedef f16 f16x4 __attribute__((ext_vector_type(4)));
typedef f16 f16x2 __attribute__((ext_vector_type(2)));
typedef float f32x4 __attribute__((ext_vector_type(4)));

__device__ __forceinline__ float lrelu(float x, float s){ return x>=0.f? x : s*x; }

// ---------------- CSR build ----------------
__global__ __launch_bounds__(256) void k_deg(const int* __restrict__ dst,
                                             int* __restrict__ deg, int E) {
  int i = blockIdx.x * 256 + threadIdx.x;
  if (i < E) atomicAdd(&deg[dst[i]], 1);
}

__global__ __launch_bounds__(1024) void k_scan1(const int* __restrict__ deg,
    int* __restrict__ row_ptr, int* __restrict__ bsum, float* __restrict__ dinv, int n) {
  int b = blockIdx.x, t = threadIdx.x, i = b * 1024 + t;
  __shared__ int sd[1024];
  int v = (i < n) ? deg[i] : 0;
  if (i < n) dinv[i] = rsqrtf((float)(v + 1));   // +1 self loop
  sd[t] = v;
  __syncthreads();
  for (int off = 1; off < 1024; off <<= 1) {
    int o = (t >= off) ? sd[t - off] : 0;
    __syncthreads();
    sd[t] += o;
    __syncthreads();
  }
  if (i < n) row_ptr[i + 1] = sd[t];
  if (t == 1023) bsum[b] = sd[1023];
  if (b == 0 && t == 0) row_ptr[0] = 0;
}

__global__ __launch_bounds__(64) void k_scan2(int* __restrict__ bsum, int nb) {
  int lane = threadIdx.x;
  int v = (lane < nb) ? bsum[lane] : 0;
  int x = v;
  for (int off = 1; off < 64; off <<= 1) {
    int o = __shfl_up(x, off, 64);
    if (lane >= off) x += o;
  }
  if (lane < nb) bsum[lane] = x - v;
}

__global__ __launch_bounds__(256) void k_scan3(int* __restrict__ row_ptr,
                                               const int* __restrict__ bsum, int n) {
  int i = blockIdx.x * 256 + threadIdx.x;
  if (i < n) row_ptr[i + 1] += bsum[i >> 10];
}

__global__ __launch_bounds__(256) void k_fill(const int* __restrict__ src,
                                              const int* __restrict__ dst,
                                              const int* __restrict__ row_ptr,
                                              const float* __restrict__ dinv,
                                              int* __restrict__ fill,
                                              int* __restrict__ csr,
                                              float* __restrict__ csrw, int E) {
  int i = blockIdx.x * 256 + threadIdx.x;
  if (i < E) {
    int d = dst[i], s = src[i];
    int pos = row_ptr[d] + atomicAdd(&fill[d], 1);
    csr[pos] = s;
    csrw[pos] = dinv[d] * dinv[s];
  }
}

// ---------------- conversions / packing ----------------
__global__ __launch_bounds__(256) void k_conv_emb(const float* __restrict__ src,
                                                  f16* __restrict__ dst, int total4) {
  int i = blockIdx.x * 256 + threadIdx.x;
  if (i >= total4) return;
  float4 v = ((const float4*)src)[i];
  f16x4 o = { (f16)v.x, (f16)v.y, (f16)v.z, (f16)v.w };
  ((f16x4*)dst)[i] = o;
}

__global__ __launch_bounds__(256) void k_pack_w(const float* __restrict__ W,
    f16* __restrict__ hi, int kb_total) {
  int idx = blockIdx.x * 256 + threadIdx.x;
  int c = idx & 127, kb = idx >> 7;
  if (kb >= kb_total) return;
  f16x8 hv;
#pragma unroll
  for (int j = 0; j < 8; j++) hv[j] = (f16)W[(size_t)(kb*8 + j) * 128 + c];
  ((f16x8*)hi)[idx] = hv;
}

__global__ __launch_bounds__(256) void k_pack_w8(const float* __restrict__ gcnW,
    const float* __restrict__ gatW, f16* __restrict__ hi, f16* __restrict__ lo) {
  int mat = blockIdx.y;
  const float* W = (mat < 4) ? gcnW + (size_t)mat * 16384 : gatW + (size_t)(mat - 4) * 16384;
  int idx = blockIdx.x * 256 + threadIdx.x;
  int c = idx & 127, kb = idx >> 7;
  f16x8 hv, lv;
#pragma unroll
  for (int j = 0; j < 8; j++) {
    float v = W[(size_t)(kb*8 + j) * 128 + c];
    f16 h = (f16)v;
    hv[j] = h; lv[j] = (f16)(v - (float)h);
  }
  ((f16x8*)hi)[mat * 2048 + idx] = hv;
  ((f16x8*)lo)[mat * 2048 + idx] = lv;
}

// ---------------- MFMA GEMM: embed-gather A (direct-load, barrier-free K-loop) --
__global__ __launch_bounds__(512) void k_mfma_embed(const int* __restrict__ poi,
    const float* __restrict__ dist, const f16* __restrict__ eh,
    const f16* __restrict__ wh, f16* __restrict__ H16, int n) {
  __shared__ __attribute__((aligned(16))) char smem[49152];
  int* poi_s = (int*)smem;                 // [2][1024] @ 0..8K (dead after K-loop)
  f16* OT    = (f16*)smem;                 // [64][128] @ 0..16K (epilogue)
  float* F   = (float*)(smem + 16384);     // [64][128] f32 @ 16K..48K
  int tid = threadIdx.x;
  int bn = blockIdx.x * 64;
  int half = tid >> 8;
  int t2 = tid & 255;
  int ln = t2 >> 2, qt = t2 & 3;
  int xrow = bn + ln; if (xrow > n - 1) xrow = n - 1;
  {
#pragma unroll
    for (int jj = 0; jj < 4; jj++)
      poi_s[half * 1024 + (qt * 4 + jj) * 64 + ln] =
        poi[(size_t)xrow * 32 + half * 16 + qt * 4 + jj];
  }
  int w2 = (tid >> 6) & 3, lane = tid & 63;
  int q = lane >> 4, l15 = lane & 15;
  int mtb = (w2 & 1) * 2;
  int ntb = (w2 >> 1) * 4;
  f32x4 acc[2][4];
#pragma unroll
  for (int a = 0; a < 2; a++)
#pragma unroll
    for (int b = 0; b < 4; b++) { acc[a][b][0]=0.f; acc[a][b][1]=0.f; acc[a][b][2]=0.f; acc[a][b][3]=0.f; }
  __syncthreads();   // poi_s ready; no further barriers until epilogue

#pragma unroll 1
  for (int j = 0; j < 16; j++) {
    // this wave's two A-row indices for tile j (from LDS, cheap)
    int rb = half * 1024 + j * 64 + mtb * 16 + l15;
    int r0 = poi_s[rb];
    int r1 = poi_s[rb + 16];
    const f16* b0 = eh + (size_t)r0 * 128 + q * 8;
    const f16* b1 = eh + (size_t)r1 * 128 + q * 8;
    f16x8 a0[4], a1[4];
#pragma unroll
    for (int kcl = 0; kcl < 4; kcl++) {      // 8 independent 16B gathers in flight
      a0[kcl] = *(const f16x8*)(b0 + kcl * 32);
      a1[kcl] = *(const f16x8*)(b1 + kcl * 32);
    }
#pragma unroll
    for (int kcl = 0; kcl < 4; kcl++) {
      int kb = (half * 16 + j) * 16 + kcl * 4 + q;
#pragma unroll
      for (int ni = 0; ni < 4; ni++) {
        f16x8 bh = *(const f16x8*)(wh + ((size_t)kb * 128 + (ntb + ni) * 16 + l15) * 8);
        acc[0][ni] = __builtin_amdgcn_mfma_f32_16x16x32_f16(a0[kcl], bh, acc[0][ni], 0, 0, 0);
        acc[1][ni] = __builtin_amdgcn_mfma_f32_16x16x32_f16(a1[kcl], bh, acc[1][ni], 0, 0, 0);
      }
    }
  }
  if (half) {
    int nc0 = bn + (mtb + 0) * 16 + l15; if (nc0 > n - 1) nc0 = n - 1;
    int nc1 = bn + (mtb + 1) * 16 + l15; if (nc1 > n - 1) nc1 = n - 1;
    f16x8 ad[2];
#pragma unroll
    for (int mi = 0; mi < 2; mi++) {
      int nc = mi ? nc1 : nc0;
      const float* dp = dist + (size_t)nc * 32 + q * 8;
      float4 d0 = *(const float4*)dp, d1 = *(const float4*)(dp + 4);
      ad[mi][0]=(f16)d0.x; ad[mi][1]=(f16)d0.y; ad[mi][2]=(f16)d0.z; ad[mi][3]=(f16)d0.w;
      ad[mi][4]=(f16)d1.x; ad[mi][5]=(f16)d1.y; ad[mi][6]=(f16)d1.z; ad[mi][7]=(f16)d1.w;
    }
    int kb = 512 + q;
#pragma unroll
    for (int ni = 0; ni < 4; ni++) {
      f16x8 bh = *(const f16x8*)(wh + ((size_t)kb * 128 + (ntb + ni) * 16 + l15) * 8);
#pragma unroll
      for (int mi = 0; mi < 2; mi++)
        acc[mi][ni] = __builtin_amdgcn_mfma_f32_16x16x32_f16(ad[mi], bh, acc[mi][ni], 0, 0, 0);
    }
  }
  __syncthreads();
  if (half) {
#pragma unroll
    for (int mi = 0; mi < 2; mi++)
#pragma unroll
      for (int ni = 0; ni < 4; ni++)
#pragma unroll
        for (int r = 0; r < 4; r++)
          F[((mtb + mi) * 16 + q * 4 + r) * 128 + (ntb + ni) * 16 + l15] = acc[mi][ni][r];
  }
  __syncthreads();
  if (!half) {
#pragma unroll
    for (int mi = 0; mi < 2; mi++)
#pragma unroll
      for (int ni = 0; ni < 4; ni++)
#pragma unroll
        for (int r = 0; r < 4; r++) {
          int o = ((mtb + mi) * 16 + q * 4 + r) * 128 + (ntb + ni) * 16 + l15;
          OT[o] = (f16)(acc[mi][ni][r] + F[o]);
        }
  }
  __syncthreads();
#pragma unroll
  for (int ch = 0; ch < 2; ch++) {
    int c1024 = tid + ch * 512;
    int row = c1024 >> 4, c8 = c1024 & 15;
    if (bn + row < n)
      *(f16x8*)(H16 + (size_t)(bn + row) * 128 + c8 * 8) = *(const f16x8*)(OT + row * 128 + c8 * 8);
  }
}

// ---------------- MFMA GEMM: K=128; fused in-block stats + residual + a-dot -----
#define LPAD 136
__global__ __launch_bounds__(256) void k_mfma_lin(const f16* __restrict__ XH,
    const f16* __restrict__ wh, const f16* __restrict__ wl,
    f16* __restrict__ H16, int n,
    const float* __restrict__ asrc, const float* __restrict__ adst,
    float* __restrict__ als, float* __restrict__ ald,
    const float* __restrict__ yres, const float* __restrict__ ps,
    const float* __restrict__ pq, const float* __restrict__ nw,
    const float* __restrict__ nbb, const float* __restrict__ nms,
    float* __restrict__ xf) {
  __shared__ __attribute__((aligned(16))) char smem[64 * LPAD * 2 + 3072];
  f16* aS = (f16*)smem;
  f16* ot = (f16*)smem;
  float* dsrc = (float*)(smem + 16384);
  float* ddst = (float*)(smem + 16896);
  float* scf  = (float*)(smem + 17408);   // [128] scale
  float* shf  = scf + 128;                // [128] shift
  float* sst1 = (float*)(smem + 18432);   // [256]
  float* sst2 = sst1 + 256;               // [256]
  int tid = threadIdx.x;
  int bn = blockIdx.x * 64;
  int ln = tid >> 2, qt = tid & 3;
  int w = tid >> 6, lane = tid & 63;
  int q = lane >> 4, l15 = lane & 15;
  int mtb = (w & 1) * 2;
  int ntb = (w >> 1) * 4;
  f16* wp = aS + ln * LPAD + qt * 32;
  if (yres) {
    // in-block GraphNorm stats from psum partials (visible via launch boundary)
    {
      int c = tid & 127, hf = tid >> 7;
      float S = 0.f, Q = 0.f;
      for (int s = hf; s < 128; s += 2) { S += ps[s * 128 + c]; Q += pq[s * 128 + c]; }
      sst1[tid] = S; sst2[tid] = Q;
      __syncthreads();
      if (hf == 0) {
        double Sd = (double)sst1[c] + (double)sst1[c + 128];
        double Qd = (double)sst2[c] + (double)sst2[c + 128];
        double invn = 1.0 / (double)n;
        double mean = Sd * invn;
        double mt = (double)nms[c] * mean;
        double var = Qd * invn - 2.0 * mt * mean + mt * mt;
        float rstd = rsqrtf((float)var + 1e-5f);
        float sc = nw[c] * rstd;
        scf[c] = sc;
        shf[c] = nbb[c] - sc * (float)mt;
      }
      __syncthreads();
    }
    // fused residual: x += lrelu(scale*y + shift); LDS gets f16(x)
    int row = bn + ln;
    if (row < n) {
      const float4* yp = (const float4*)(yres + (size_t)row * 128 + qt * 32);
      float4* xp = (float4*)(xf + (size_t)row * 128 + qt * 32);
      const float4* scp = (const float4*)(scf + qt * 32);
      const float4* shp = (const float4*)(shf + qt * 32);
#pragma unroll
      for (int jj = 0; jj < 8; jj++) {
        float4 yv = yp[jj], xv = xp[jj], sc = scp[jj], sh = shp[jj];
        xv.x += lrelu(sc.x * yv.x + sh.x, 0.01f);
        xv.y += lrelu(sc.y * yv.y + sh.y, 0.01f);
        xv.z += lrelu(sc.z * yv.z + sh.z, 0.01f);
        xv.w += lrelu(sc.w * yv.w + sh.w, 0.01f);
        xp[jj] = xv;
        f16x4 o = { (f16)xv.x, (f16)xv.y, (f16)xv.z, (f16)xv.w };
        *(f16x4*)(wp + jj * 4) = o;
      }
    } else {
      f16x8 z = {};
#pragma unroll
      for (int jj = 0; jj < 4; jj++) *(f16x8*)(wp + jj * 8) = z;
    }
  } else {
    int xrow = bn + ln; if (xrow > n - 1) xrow = n - 1;
    const f16* srcp = XH + (size_t)xrow * 128 + qt * 32;
    *(f16x8*)(wp)      = *(const f16x8*)(srcp);
    *(f16x8*)(wp + 8)  = *(const f16x8*)(srcp + 8);
    *(f16x8*)(wp + 16) = *(const f16x8*)(srcp + 16);
    *(f16x8*)(wp + 24) = *(const f16x8*)(srcp + 24);
  }
  float av[4], bv[4];
  if (asrc) {
#pragma unroll
    for (int ni = 0; ni < 4; ni++) {
      av[ni] = asrc[(ntb + ni) * 16 + l15];
      bv[ni] = adst[(ntb + ni) * 16 + l15];
    }
  }
  f32x4 acc[2][4];
#pragma unroll
  for (int a = 0; a < 2; a++)
#pragma unroll
    for (int b = 0; b < 4; b++) { acc[a][b][0]=0.f; acc[a][b][1]=0.f; acc[a][b][2]=0.f; acc[a][b][3]=0.f; }
  __syncthreads();
#pragma unroll
  for (int kcl = 0; kcl < 4; kcl++) {
    f16x8 a_h[2];
#pragma unroll
    for (int mi = 0; mi < 2; mi++)
      a_h[mi] = *(const f16x8*)(aS + ((mtb + mi) * 16 + l15) * LPAD + kcl * 32 + q * 8);
    int kb = kcl * 4 + q;
#pragma unroll
    for (int ni = 0; ni < 4; ni++) {
      size_t boff = ((size_t)kb * 128 + (ntb + ni) * 16 + l15) * 8;
      f16x8 bh = *(const f16x8*)(wh + boff);
      f16x8 bl = *(const f16x8*)(wl + boff);
#pragma unroll
      for (int mi = 0; mi < 2; mi++) {
        acc[mi][ni] = __builtin_amdgcn_mfma_f32_16x16x32_f16(a_h[mi], bh, acc[mi][ni], 0, 0, 0);
        acc[mi][ni] = __builtin_amdgcn_mfma_f32_16x16x32_f16(a_h[mi], bl, acc[mi][ni], 0, 0, 0);
      }
    }
  }
  __syncthreads();
  if (asrc) {
#pragma unroll
    for (int mi = 0; mi < 2; mi++)
#pragma unroll
      for (int r = 0; r < 4; r++) {
        float ps2 = 0.f, pd = 0.f;
#pragma unroll
        for (int ni = 0; ni < 4; ni++) { ps2 += acc[mi][ni][r] * av[ni]; pd += acc[mi][ni][r] * bv[ni]; }
#pragma unroll
        for (int msk = 8; msk > 0; msk >>= 1) {
          ps2 += __shfl_xor(ps2, msk, 64);
          pd += __shfl_xor(pd, msk, 64);
        }
        if (l15 == 0) {
          int row = (mtb + mi) * 16 + q * 4 + r;
          dsrc[row * 2 + (w >> 1)] = ps2;
          ddst[row * 2 + (w >> 1)] = pd;
        }
      }
  }
#pragma unroll
  for (int mi = 0; mi < 2; mi++)
#pragma unroll
    for (int ni = 0; ni < 4; ni++)
#pragma unroll
      for (int r = 0; r < 4; r++)
        ot[((mtb + mi) * 16 + q * 4 + r) * 128 + (ntb + ni) * 16 + l15] = (f16)acc[mi][ni][r];
  __syncthreads();
  if (bn + ln < n) {
    f16* dst = H16 + (size_t)(bn + ln) * 128 + qt * 32;
    const f16* srcp = ot + ln * 128 + qt * 32;
#pragma unroll
    for (int jj = 0; jj < 4; jj++)
      *(f16x8*)(dst + jj * 8) = *(const f16x8*)(srcp + jj * 8);
  }
  if (asrc && tid < 64 && bn + tid < n) {
    als[bn + tid] = dsrc[tid * 2] + dsrc[tid * 2 + 1];
    ald[bn + tid] = ddst[tid * 2] + ddst[tid * 2 + 1];
  }
}

// ---------------- GCN aggregation: 8-wide gather rounds + fused column stats ----
__global__ __launch_bounds__(256) void k_gcn_agg16(const f16x2* __restrict__ H2,
    const float* __restrict__ dinv, const int* __restrict__ row_ptr,
    const int* __restrict__ csr, const float* __restrict__ csrw,
    const float* __restrict__ bias,
    float2* __restrict__ out2, f16x2* __restrict__ xh_out, int n, int leaky_flag,
    float* __restrict__ psum, float* __restrict__ psumsq) {
  int w = threadIdx.x >> 6;
  int node = blockIdx.x * 4 + w;
  int lane = threadIdx.x & 63;
  __shared__ float s1[4][128], s2[4][128];
  float vx = 0.f, vy = 0.f;
  if (node < n) {
    int rs = row_ptr[node], re = row_ptr[node + 1];
    int d = re - rs;
    float dn = dinv[node];
    int  sidx = (lane < d) ? csr[rs + lane]  : 0;
    float swt = (lane < d) ? csrw[rs + lane] : 0.f;
    f16x2 sv = H2[(size_t)node * 64 + lane];
    float ax = dn * dn * (float)sv[0], ay = dn * dn * (float)sv[1];
    int dl = d < 64 ? d : 64;
    int dl8 = (dl + 7) & ~7;      // padded rounds: 8 independent gathers in flight
    for (int j = 0; j < dl8; j += 8) {
      int ii[8]; float ww[8];
#pragma unroll
      for (int u = 0; u < 8; u++) {
        ii[u] = __shfl(sidx, j + u, 64);
        ww[u] = __shfl(swt,  j + u, 64);
      }
      f16x2 vv[8];
#pragma unroll
      for (int u = 0; u < 8; u++) vv[u] = H2[(size_t)ii[u] * 64 + lane];
#pragma unroll
      for (int u = 0; u < 8; u++) {
        ax += ww[u] * (float)vv[u][0];
        ay += ww[u] * (float)vv[u][1];
      }
    }
    for (int e = rs + 64; e < re; e++) {   // rare deg>64 tail
      int s = csr[e]; float wv = csrw[e];
      f16x2 v = H2[(size_t)s * 64 + lane];
      ax += wv * (float)v[0]; ay += wv * (float)v[1];
    }
    float2 bvv = ((const float2*)bias)[lane];
    vx = ax + bvv.x; vy = ay + bvv.y;
    if (leaky_flag) { vx = lrelu(vx, 0.01f); vy = lrelu(vy, 0.01f); }
    out2[(size_t)node * 64 + lane] = make_float2(vx, vy);
    if (xh_out) { f16x2 o = { (f16)vx, (f16)vy }; xh_out[(size_t)node * 64 + lane] = o; }
  }
  if (psum) {
    s1[w][2*lane] = vx;  s1[w][2*lane+1] = vy;
    s2[w][2*lane] = vx*vx; s2[w][2*lane+1] = vy*vy;
    __syncthreads();
    int t = threadIdx.x;
    if (t < 128) {
      float S = s1[0][t] + s1[1][t] + s1[2][t] + s1[3][t];
      float Q = s2[0][t] + s2[1][t] + s2[2][t] + s2[3][t];
      int slot = blockIdx.x & 127;
      atomicAdd(&psum[slot * 128 + t], S);
      atomicAdd(&psumsq[slot * 128 + t], Q);
    }
  }
}

// ---------------- GAT aggregation: 8-wide gather rounds + fused stats ----------
__global__ __launch_bounds__(256) void k_gat_agg16(const f16x2* __restrict__ H2,
    const float* __restrict__ als, const float* __restrict__ ald,
    const int* __restrict__ row_ptr, const int* __restrict__ csr,
    const float* __restrict__ bias, float2* __restrict__ y2, int n,
    float* __restrict__ psum, float* __restrict__ psumsq) {
  int w = threadIdx.x >> 6;
  int node = blockIdx.x * 4 + w;
  int lane = threadIdx.x & 63;
  __shared__ float s1[4][128], s2[4][128];
  float vx = 0.f, vy = 0.f;
  if (node < n) {
    int rs = row_ptr[node], re = row_ptr[node + 1];
    int d = re - rs;
    float aldn = ald[node];
    float e_self = lrelu(als[node] + aldn, 0.2f);
    f16x2 sv = H2[(size_t)node * 64 + lane];
    float ax, ay, sm;
    if (d <= 64) {
      int sidx = (lane < d) ? csr[rs + lane] : 0;
      float e_k = (lane < d) ? lrelu(als[sidx] + aldn, 0.2f) : -3.4e38f;
      float tmx = e_k;
      for (int off = 1; off < 64; off <<= 1) tmx = fmaxf(tmx, __shfl_xor(tmx, off, 64));
      float mx = fmaxf(e_self, tmx);
      float g_k = (lane < d) ? __expf(e_k - mx) : 0.f;   // pad lanes weight 0
      float tsm = g_k;
      for (int off = 1; off < 64; off <<= 1) tsm += __shfl_xor(tsm, off, 64);
      float ws = __expf(e_self - mx);
      sm = tsm + ws;
      ax = ws * (float)sv[0]; ay = ws * (float)sv[1];
      int d8 = (d + 7) & ~7;     // padded rounds: 8 independent gathers in flight
      for (int j = 0; j < d8; j += 8) {
        int ii[8]; float gg[8];
#pragma unroll
        for (int u = 0; u < 8; u++) {
          ii[u] = __shfl(sidx, j + u, 64);
          gg[u] = __shfl(g_k,  j + u, 64);
        }
        f16x2 vv[8];
#pragma unroll
        for (int u = 0; u < 8; u++) vv[u] = H2[(size_t)ii[u] * 64 + lane];
#pragma unroll
        for (int u = 0; u < 8; u++) {
          ax += gg[u] * (float)vv[u][0];
          ay += gg[u] * (float)vv[u][1];
        }
      }
    } else {  // rare deg>64 slow path
      float mx = e_self;
      for (int i = rs + lane; i < re; i += 64) mx = fmaxf(mx, lrelu(als[csr[i]] + aldn, 0.2f));
      for (int off = 1; off < 64; off <<= 1) mx = fmaxf(mx, __shfl_xor(mx, off, 64));
      float ws = __expf(e_self - mx);
      sm = ws;
      ax = ws * (float)sv[0]; ay = ws * (float)sv[1];
      for (int i = rs; i < re; i++) {
        int s = csr[i];
        float g = __expf(lrelu(als[s] + aldn, 0.2f) - mx);
        f16x2 v = H2[(size_t)s * 64 + lane];
        sm += g; ax += g*(float)v[0]; ay += g*(float)v[1];
      }
    }
    float inv_s = 1.f / sm;
    float2 bvv = ((const float2*)bias)[lane];
    vx = ax * inv_s + bvv.x; vy = ay * inv_s + bvv.y;
    y2[(size_t)node * 64 + lane] = make_float2(vx, vy);
  }
  s1[w][2*lane] = vx;  s1[w][2*lane+1] = vy;
  s2[w][2*lane] = vx*vx; s2[w][2*lane+1] = vy*vy;
  __syncthreads();
  int t = threadIdx.x;
  if (t < 128) {
    float S = s1[0][t] + s1[1][t] + s1[2][t] + s1[3][t];
    float Q = s2[0][t] + s2[1][t] + s2[2][t] + s2[3][t];
    int slot = blockIdx.x & 127;
    atomicAdd(&psum[slot * 128 + t], S);
    atomicAdd(&psumsq[slot * 128 + t], Q);
  }
}

// ---------------- GraphNorm stats (single use: final GAT stats for head) -------
__global__ __launch_bounds__(256) void k_stats(const float* __restrict__ psum,
    const float* __restrict__ psumsq, const float* __restrict__ w,
    const float* __restrict__ bb, const float* __restrict__ ms,
    float* __restrict__ scaleA, float* __restrict__ shiftA, int n) {
  int t = threadIdx.x, c = t & 127, half = t >> 7;
  float S = 0.f, Q = 0.f;
  for (int s = half; s < 128; s += 2) { S += psum[s * 128 + c]; Q += psumsq[s * 128 + c]; }
  __shared__ float sh[256], sq[256];
  sh[t] = S; sq[t] = Q;
  __syncthreads();
  if (half == 0) {
    double Sd = (double)sh[c] + (double)sh[c + 128];
    double Qd = (double)sq[c] + (double)sq[c + 128];
    double invn = 1.0 / (double)n;
    double mean = Sd * invn;
    double mt = (double)ms[c] * mean;
    double var = Qd * invn - 2.0 * mt * mean + mt * mt;
    float rstd = rsqrtf((float)var + 1e-5f);
    float sc = w[c] * rstd;
    scaleA[c] = sc;
    shiftA[c] = bb[c] - sc * (float)mt;
  }
}

// ---------------- Output head: final residual fused into the W_out dot -------
__global__ __launch_bounds__(256) void k_dot1_res(const float* __restrict__ y,
    const float* __restrict__ scA, const float* __restrict__ shA,
    const float* __restrict__ x, const float* __restrict__ wv,
    float* __restrict__ o, int n) {
  int node = blockIdx.x * 4 + (threadIdx.x >> 6);
  int lane = threadIdx.x & 63;
  if (node >= n) return;
  float2 yv = ((const float2*)y)[(size_t)node * 64 + lane];
  float2 xv = ((const float2*)x)[(size_t)node * 64 + lane];
  float2 sc = ((const float2*)scA)[lane];
  float2 sh = ((const float2*)shA)[lane];
  float hx = xv.x + lrelu(sc.x * yv.x + sh.x, 0.01f);
  float hy = xv.y + lrelu(sc.y * yv.y + sh.y, 0.01f);
  float2 v1 = ((const float2*)wv)[lane];
  float s1 = hx * v1.x + hy * v1.y;
  for (int off = 32; off > 0; off >>= 1) s1 += __shfl_down(s1, off, 64);
  if (lane == 0) o[node] = s1;
}

__global__ __launch_bounds__(256) void k_scalar_agg(const float* __restrict__ xsv,
    const float* __restrict__ dinv, const int* __restrict__ row_ptr,
    const int* __restrict__ csr, const float* __restrict__ csrw,
    const float* __restrict__ b_out, float* __restrict__ xout, int n) {
  int i = blockIdx.x * 256 + threadIdx.x;
  if (i >= n) return;
  float dn = dinv[i];
  float acc = dn * dn * xsv[i];
  int re = row_ptr[i + 1];
  for (int e = row_ptr[i]; e < re; e++)
    acc += csrw[e] * xsv[csr[e]];
  xout[i] = lrelu(acc + b_out[0], 0.01f);
}

__global__ __launch_bounds__(256) void k_fc1(const float* __restrict__ xout,
    const float* __restrict__ fw, float* __restrict__ pfc, int n, int chunk) {
  int b = blockIdx.x, t = threadIdx.x;
  int c = t & 127, half = t >> 7;
  int s0 = b * chunk;
  int s1 = s0 + chunk; if (s1 > n) s1 = n;
  float s = 0.f;
  for (int i = s0 + half; i < s1; i += 2) s += xout[i] * fw[(size_t)i * 128 + c];
  __shared__ float sh[256];
  sh[t] = s; __syncthreads();
  if (half == 0) pfc[b * 128 + c] = sh[c] + sh[c + 128];
}

__global__ __launch_bounds__(128) void k_final(const float* __restrict__ pfc,
    const float* __restrict__ b1, const float* __restrict__ fw2,
    const float* __restrict__ b2, float* __restrict__ out) {
  int c = threadIdx.x;
  float s = 0.f;
  for (int b = 0; b < 128; b++) s += pfc[b * 128 + c];
  float hv = lrelu(s + b1[c], 0.01f);
  __shared__ float h1[128];
  h1[c] = hv; __syncthreads();
  float o = b2[c];
  for (int j = 0; j < 128; j++) o += h1[j] * fw2[j * 128 + c];
  out[c] = o;
}

// ---------------- host ----------------
extern "C" void kernel_launch(void* const* d_in, const int* in_sizes, int n_in,
                              void* d_out, int out_size, void* d_ws, size_t ws_size,
                              hipStream_t stream) {
  const int* poi      = (const int*)d_in[0];
  const float* dist   = (const float*)d_in[1];
  const int* ei       = (const int*)d_in[2];
  const float* emb    = (const float*)d_in[3];
  const float* W_in   = (const float*)d_in[4];
  const float* b_in   = (const float*)d_in[5];
  const float* gcn_W  = (const float*)d_in[6];
  const float* gcn_b  = (const float*)d_in[7];
  const float* norm_w = (const float*)d_in[8];
  const float* norm_b = (const float*)d_in[9];
  const float* norm_ms= (const float*)d_in[10];
  const float* gat_W  = (const float*)d_in[11];
  const float* gat_as = (const float*)d_in[12];
  const float* gat_ad = (const float*)d_in[13];
  const float* gat_b  = (const float*)d_in[14];
  const float* W_out  = (const float*)d_in[15];
  const float* b_out  = (const float*)d_in[16];
  const float* fc1_W  = (const float*)d_in[17];
  const float* fc1_b  = (const float*)d_in[18];
  const float* fc2_W  = (const float*)d_in[19];
  const float* fc2_b  = (const float*)d_in[20];

  const int N   = in_sizes[0] / 32;
  const int E   = in_sizes[2] / 2;
  const int POI = in_sizes[3] / 128;
  const int* srcp = ei;
  const int* dstp = ei + E;
  float* out = (float*)d_out;

  char* p = (char*)d_ws;
  auto alloc = [&](size_t bytes) { char* r = p; p += (bytes + 255) & ~(size_t)255; return r; };
  float* x   = (float*)alloc((size_t)N * 128 * 4);
  f16* h16   = (f16*)alloc((size_t)N * 128 * 2);
  f16* xh    = (f16*)alloc((size_t)N * 128 * 2);
  size_t Rneed = (size_t)POI * 128 * 2;
  size_t Ry    = (size_t)N * 128 * 4;
  char* R = alloc(Rneed > Ry ? Rneed : Ry);
  f16* ehalf = (f16*)R;
  float* y   = (float*)R;
  const int KBIN = 4128 / 8;
  f16* wih = (f16*)alloc((size_t)KBIN * 128 * 8 * 2);
  f16* wsh = (f16*)alloc((size_t)8 * 16384 * 2);
  f16* wsl = (f16*)alloc((size_t)8 * 16384 * 2);
  float* dinv   = (float*)alloc((size_t)N * 4);
  float* als    = (float*)alloc((size_t)N * 4);
  float* ald    = (float*)alloc((size_t)N * 4);
  float* xsv    = (float*)alloc((size_t)N * 4);
  float* xout   = (float*)alloc((size_t)N * 4);
  float* statsbuf = (float*)alloc((size_t)32 * 16384 * 4);   // 2 MB
  float* pfc    = (float*)alloc(128 * 128 * 4);
  float* scaleA = (float*)alloc(128 * 4);
  float* shiftA = (float*)alloc(128 * 4);
  int* deg     = (int*)alloc((size_t)N * 2 * 4);
  int* fill    = deg + N;
  int* row_ptr = (int*)alloc(((size_t)N + 1) * 4);
  int* csr     = (int*)alloc((size_t)E * 4);
  float* csrw  = (float*)alloc((size_t)E * 4);
  int* bsum    = (int*)alloc(64 * 4);

  const int chunk = (N + 127) / 128;
  const int gblocks = (N + 63) / 64;
  const int eblocks = (E + 255) / 256;
  const int nwb = (N + 3) / 4;
  const int nb1024 = (N + 1023) / 1024;

  hipMemsetAsync(deg, 0, sizeof(int) * 2 * (size_t)N, stream);
  hipMemsetAsync(statsbuf, 0, (size_t)32 * 16384 * 4, stream);
  k_deg<<<eblocks, 256, 0, stream>>>(dstp, deg, E);
  k_scan1<<<nb1024, 1024, 0, stream>>>(deg, row_ptr, bsum, dinv, N);
  k_scan2<<<1, 64, 0, stream>>>(bsum, nb1024);
  k_scan3<<<(N + 255) / 256, 256, 0, stream>>>(row_ptr, bsum, N);
  k_fill<<<eblocks, 256, 0, stream>>>(srcp, dstp, row_ptr, dinv, fill, csr, csrw, E);

  int et4 = POI * 128 / 4;
  k_conv_emb<<<(et4 + 255) / 256, 256, 0, stream>>>(emb, ehalf, et4);
  k_pack_w<<<(KBIN * 128 + 255) / 256, 256, 0, stream>>>(W_in, wih, KBIN);
  k_pack_w8<<<dim3(8, 8), 256, 0, stream>>>(gcn_W, gat_W, wsh, wsl);

  // input layer
  k_mfma_embed<<<gblocks, 512, 0, stream>>>(poi, dist, ehalf, wih, h16, N);
  k_gcn_agg16<<<nwb, 256, 0, stream>>>((const f16x2*)h16, dinv, row_ptr, csr, csrw, b_in,
                                       (float2*)x, (f16x2*)xh, N, 1, nullptr, nullptr);

  for (int l = 0; l < 4; l++) {
    const f16* gh = wsh + (size_t)l * 16384;
    const f16* gl = wsl + (size_t)l * 16384;
    const f16* th = wsh + (size_t)(4 + l) * 16384;
    const f16* tl = wsl + (size_t)(4 + l) * 16384;
    float* ps0 = statsbuf + (size_t)(4 * l) * 16384;   // gcn psum (layer l)
    float* pq0 = ps0 + 16384;
    float* ps1 = ps0 + 2 * 16384;                      // gat psum (layer l)
    float* pq1 = ps0 + 3 * 16384;
    // GCN sub-unit: lin consumes previous-layer GAT stats (residual) for l>0
    if (l == 0)
      k_mfma_lin<<<gblocks, 256, 0, stream>>>(xh, gh, gl, h16, N,
          nullptr, nullptr, nullptr, nullptr,
          nullptr, nullptr, nullptr, nullptr, nullptr, nullptr, nullptr);
    else {
      float* ps1p = statsbuf + (size_t)(4 * (l - 1) + 2) * 16384;
      float* pq1p = ps1p + 16384;
      k_mfma_lin<<<gblocks, 256, 0, stream>>>(nullptr, gh, gl, h16, N,
          nullptr, nullptr, nullptr, nullptr,
          y, ps1p, pq1p, norm_w + (l - 1) * 128, norm_b + (l - 1) * 128,
          norm_ms + (l - 1) * 128, x);
    }
    k_gcn_agg16<<<nwb, 256, 0, stream>>>((const f16x2*)h16, dinv, row_ptr, csr, csrw,
                                         gcn_b + l * 128, (float2*)y, (f16x2*)nullptr, N, 0,
                                         ps0, pq0);
    // GAT sub-unit: lin consumes this layer's GCN stats (residual); a-dot fused
    k_mfma_lin<<<gblocks, 256, 0, stream>>>(nullptr, th, tl, h16, N,
        gat_as + l * 128, gat_ad + l * 128, als, ald,
        y, ps0, pq0, norm_w + l * 128, norm_b + l * 128, norm_ms + l * 128, x);
    k_gat_agg16<<<nwb, 256, 0, stream>>>((const f16x2*)h16, als, ald, row_ptr, csr,
                                         gat_b + l * 128, (float2*)y, N, ps1, pq1);
  }

  // output head: single k_stats for the final GAT norm, then fused dot
  {
    float* ps1 = statsbuf + (size_t)(4 * 3 + 2) * 16384;
    float* pq1 = ps1 + 16384;
    k_stats<<<1, 256, 0, stream>>>(ps1, pq1, norm_w + 3 * 128, norm_b + 3 * 128,
                                   norm_ms + 3 * 128, scaleA, shiftA, N);
  }
  k_dot1_res<<<nwb, 256, 0, stream>>>(y, scaleA, shiftA, x, W_out, xsv, N);
  k_scalar_agg<<<(N + 255) / 256, 256, 0, stream>>>(xsv, dinv, row_ptr, csr, csrw, b_out, xout, N);
  k_fc1<<<128, 256, 0, stream>>>(xout, fc1_W, pfc, N, chunk);
  k_final<<<1, 128, 0, stream>>>(pfc, fc1_b, fc2_W, fc2_b, out);
}

// Round 9
// 972.033 us; speedup vs baseline: 1.0914x; 1.0374x over previous
//
#include <hip/hip_runtime.h>

// GlobalDistNet forward, round 16:
//  - EXACT r12 composition restored (981 us measured best):
//    embed = r9 staged body (110MB fetch @ ~1TB/s = its floor; direct-load r15
//    regressed via 4x L2 request inflation), aggs = 8-wide gather rounds
//    (fabric request-rate bound; L2-capacity splits r13/r14 both refuted),
//    stats fused into k_mfma_lin prologue, residual fusion, 1 k_stats.
//  - NEW (only change): k_deg/k_conv_emb/k_pack_w/k_pack_w8 merged into one
//    k_prep kernel partitioned by block range (-3 serialized launches).

typedef _Float16 f16;
typedef f16 f16x8 __attribute__((ext_vector_type(8)));
typedef f16 f16x4 __attribute__((ext_vector_type(4)));
typedef f16 f16x2 __attribute__((ext_vector_type(2)));
typedef float f32x4 __attribute__((ext_vector_type(4)));

__device__ __forceinline__ float lrelu(float x, float s){ return x>=0.f? x : s*x; }

// ---------------- merged prep: deg + emb-convert + W_in pack + gcn/gat pack ----
__global__ __launch_bounds__(256) void k_prep(
    const int* __restrict__ dst, int* __restrict__ deg, int E, int ebl,
    const float* __restrict__ emb, f16* __restrict__ eh, int et4, int cbl,
    const float* __restrict__ W_in, f16* __restrict__ wih, int kbin, int pbl,
    const float* __restrict__ gcnW, const float* __restrict__ gatW,
    f16* __restrict__ wsh, f16* __restrict__ wsl) {
  int b = blockIdx.x, t = threadIdx.x;
  if (b < ebl) {                       // k_deg
    int i = b * 256 + t;
    if (i < E) atomicAdd(&deg[dst[i]], 1);
    return;
  }
  b -= ebl;
  if (b < cbl) {                       // k_conv_emb
    int i = b * 256 + t;
    if (i < et4) {
      float4 v = ((const float4*)emb)[i];
      f16x4 o = { (f16)v.x, (f16)v.y, (f16)v.z, (f16)v.w };
      ((f16x4*)eh)[i] = o;
    }
    return;
  }
  b -= cbl;
  if (b < pbl) {                       // k_pack_w (W_in)
    int idx = b * 256 + t;
    int c = idx & 127, kb = idx >> 7;
    if (kb < kbin) {
      f16x8 hv;
#pragma unroll
      for (int j = 0; j < 8; j++) hv[j] = (f16)W_in[(size_t)(kb*8 + j) * 128 + c];
      ((f16x8*)wih)[idx] = hv;
    }
    return;
  }
  b -= pbl;
  {                                    // k_pack_w8 (gcn/gat hi+lo)
    int mat = b >> 3, bx = b & 7;
    const float* W = (mat < 4) ? gcnW + (size_t)mat * 16384 : gatW + (size_t)(mat - 4) * 16384;
    int idx = bx * 256 + t;
    int c = idx & 127, kb = idx >> 7;
    f16x8 hv, lv;
#pragma unroll
    for (int j = 0; j < 8; j++) {
      float v = W[(size_t)(kb*8 + j) * 128 + c];
      f16 h = (f16)v;
      hv[j] = h; lv[j] = (f16)(v - (float)h);
    }
    ((f16x8*)wsh)[mat * 2048 + idx] = hv;
    ((f16x8*)wsl)[mat * 2048 + idx] = lv;
  }
}

// ---------------- CSR build ----------------
__global__ __launch_bounds__(1024) void k_scan1(const int* __restrict__ deg,
    int* __restrict__ row_ptr, int* __restrict__ bsum, float* __restrict__ dinv, int n) {
  int b = blockIdx.x, t = threadIdx.x, i = b * 1024 + t;
  __shared__ int sd[1024];
  int v = (i < n) ? deg[i] : 0;
  if (i < n) dinv[i] = rsqrtf((float)(v + 1));   // +1 self loop
  sd[t] = v;
  __syncthreads();
  for (int off = 1; off < 1024; off <<= 1) {
    int o = (t >= off) ? sd[t - off] : 0;
    __syncthreads();
    sd[t] += o;
    __syncthreads();
  }
  if (i < n) row_ptr[i + 1] = sd[t];
  if (t == 1023) bsum[b] = sd[1023];
  if (b == 0 && t == 0) row_ptr[0] = 0;
}

__global__ __launch_bounds__(64) void k_scan2(int* __restrict__ bsum, int nb) {
  int lane = threadIdx.x;
  int v = (lane < nb) ? bsum[lane] : 0;
  int x = v;
  for (int off = 1; off < 64; off <<= 1) {
    int o = __shfl_up(x, off, 64);
    if (lane >= off) x += o;
  }
  if (lane < nb) bsum[lane] = x - v;
}

__global__ __launch_bounds__(256) void k_scan3(int* __restrict__ row_ptr,
                                               const int* __restrict__ bsum, int n) {
  int i = blockIdx.x * 256 + threadIdx.x;
  if (i < n) row_ptr[i + 1] += bsum[i >> 10];
}

__global__ __launch_bounds__(256) void k_fill(const int* __restrict__ src,
                                              const int* __restrict__ dst,
                                              const int* __restrict__ row_ptr,
                                              const float* __restrict__ dinv,
                                              int* __restrict__ fill,
                                              int* __restrict__ csr,
                                              float* __restrict__ csrw, int E) {
  int i = blockIdx.x * 256 + threadIdx.x;
  if (i < E) {
    int d = dst[i], s = src[i];
    int pos = row_ptr[d] + atomicAdd(&fill[d], 1);
    csr[pos] = s;
    csrw[pos] = dinv[d] * dinv[s];
  }
}

// ---------------- MFMA GEMM: embed-gather A, K=4128, dual K-half block ------------
#define APAD 152
__global__ __launch_bounds__(512) void k_mfma_embed(const int* __restrict__ poi,
    const float* __restrict__ dist, const f16* __restrict__ eh,
    const f16* __restrict__ wh, f16* __restrict__ H16, int n) {
  __shared__ __attribute__((aligned(16))) char smem[49152];
  int* poi_s = (int*)smem;
  f16* aS    = (f16*)(smem + 8192);
  f16* OT    = (f16*)smem;
  float* F   = (float*)(smem + 16384);
  int tid = threadIdx.x;
  int bn = blockIdx.x * 64;
  int half = tid >> 8;
  int t2 = tid & 255;
  int ln = t2 >> 2, qt = t2 & 3;
  int xrow = bn + ln; if (xrow > n - 1) xrow = n - 1;
  {
#pragma unroll
    for (int jj = 0; jj < 4; jj++)
      poi_s[half * 1024 + (qt * 4 + jj) * 64 + ln] =
        poi[(size_t)xrow * 32 + half * 16 + qt * 4 + jj];
  }
  int w2 = (tid >> 6) & 3, lane = tid & 63;
  int q = lane >> 4, l15 = lane & 15;
  int mtb = (w2 & 1) * 2;
  int ntb = (w2 >> 1) * 4;
  f16* aH = aS + half * 64 * APAD;
  f32x4 acc[2][4];
#pragma unroll
  for (int a = 0; a < 2; a++)
#pragma unroll
    for (int b = 0; b < 4; b++) { acc[a][b][0]=0.f; acc[a][b][1]=0.f; acc[a][b][2]=0.f; acc[a][b][3]=0.f; }
  __syncthreads();

  f16x8 r0, r1, r2, r3;
  {
    const f16* srcp = eh + (size_t)poi_s[half * 1024 + ln] * 128 + qt * 32;
    r0 = *(const f16x8*)(srcp);      r1 = *(const f16x8*)(srcp + 8);
    r2 = *(const f16x8*)(srcp + 16); r3 = *(const f16x8*)(srcp + 24);
  }

#pragma unroll 1
  for (int j = 0; j < 16; j++) {
    __syncthreads();
    f16* wp = aH + ln * APAD + qt * 32;
    *(f16x8*)(wp) = r0; *(f16x8*)(wp + 8) = r1;
    *(f16x8*)(wp + 16) = r2; *(f16x8*)(wp + 24) = r3;
    if (j + 1 < 16) {
      const f16* srcp = eh + (size_t)poi_s[half * 1024 + (j + 1) * 64 + ln] * 128 + qt * 32;
      r0 = *(const f16x8*)(srcp);      r1 = *(const f16x8*)(srcp + 8);
      r2 = *(const f16x8*)(srcp + 16); r3 = *(const f16x8*)(srcp + 24);
    }
    __syncthreads();
#pragma unroll
    for (int kcl = 0; kcl < 4; kcl++) {
      f16x8 a_h[2];
#pragma unroll
      for (int mi = 0; mi < 2; mi++)
        a_h[mi] = *(const f16x8*)(aH + ((mtb + mi) * 16 + l15) * APAD + kcl * 32 + q * 8);
      int kb = (half * 16 + j) * 16 + kcl * 4 + q;
#pragma unroll
      for (int ni = 0; ni < 4; ni++) {
        f16x8 bh = *(const f16x8*)(wh + ((size_t)kb * 128 + (ntb + ni) * 16 + l15) * 8);
#pragma unroll
        for (int mi = 0; mi < 2; mi++)
          acc[mi][ni] = __builtin_amdgcn_mfma_f32_16x16x32_f16(a_h[mi], bh, acc[mi][ni], 0, 0, 0);
      }
    }
  }
  if (half) {
    int nc0 = bn + (mtb + 0) * 16 + l15; if (nc0 > n - 1) nc0 = n - 1;
    int nc1 = bn + (mtb + 1) * 16 + l15; if (nc1 > n - 1) nc1 = n - 1;
    f16x8 ad[2];
#pragma unroll
    for (int mi = 0; mi < 2; mi++) {
      int nc = mi ? nc1 : nc0;
      const float* dp = dist + (size_t)nc * 32 + q * 8;
      float4 d0 = *(const float4*)dp, d1 = *(const float4*)(dp + 4);
      ad[mi][0]=(f16)d0.x; ad[mi][1]=(f16)d0.y; ad[mi][2]=(f16)d0.z; ad[mi][3]=(f16)d0.w;
      ad[mi][4]=(f16)d1.x; ad[mi][5]=(f16)d1.y; ad[mi][6]=(f16)d1.z; ad[mi][7]=(f16)d1.w;
    }
    int kb = 512 + q;
#pragma unroll
    for (int ni = 0; ni < 4; ni++) {
      f16x8 bh = *(const f16x8*)(wh + ((size_t)kb * 128 + (ntb + ni) * 16 + l15) * 8);
#pragma unroll
      for (int mi = 0; mi < 2; mi++)
        acc[mi][ni] = __builtin_amdgcn_mfma_f32_16x16x32_f16(ad[mi], bh, acc[mi][ni], 0, 0, 0);
    }
  }
  __syncthreads();
  if (half) {
#pragma unroll
    for (int mi = 0; mi < 2; mi++)
#pragma unroll
      for (int ni = 0; ni < 4; ni++)
#pragma unroll
        for (int r = 0; r < 4; r++)
          F[((mtb + mi) * 16 + q * 4 + r) * 128 + (ntb + ni) * 16 + l15] = acc[mi][ni][r];
  }
  __syncthreads();
  if (!half) {
#pragma unroll
    for (int mi = 0; mi < 2; mi++)
#pragma unroll
      for (int ni = 0; ni < 4; ni++)
#pragma unroll
        for (int r = 0; r < 4; r++) {
          int o = ((mtb + mi) * 16 + q * 4 + r) * 128 + (ntb + ni) * 16 + l15;
          OT[o] = (f16)(acc[mi][ni][r] + F[o]);
        }
  }
  __syncthreads();
#pragma unroll
  for (int ch = 0; ch < 2; ch++) {
    int c1024 = tid + ch * 512;
    int row = c1024 >> 4, c8 = c1024 & 15;
    if (bn + row < n)
      *(f16x8*)(H16 + (size_t)(bn + row) * 128 + c8 * 8) = *(const f16x8*)(OT + row * 128 + c8 * 8);
  }
}

// ---------------- MFMA GEMM: K=128; fused in-block stats + residual + a-dot -----
#define LPAD 136
__global__ __launch_bounds__(256) void k_mfma_lin(const f16* __restrict__ XH,
    const f16* __restrict__ wh, const f16* __restrict__ wl,
    f16* __restrict__ H16, int n,
    const float* __restrict__ asrc, const float* __restrict__ adst,
    float* __restrict__ als, float* __restrict__ ald,
    const float* __restrict__ yres, const float* __restrict__ ps,
    const float* __restrict__ pq, const float* __restrict__ nw,
    const float* __restrict__ nbb, const float* __restrict__ nms,
    float* __restrict__ xf) {
  __shared__ __attribute__((aligned(16))) char smem[64 * LPAD * 2 + 3072];
  f16* aS = (f16*)smem;
  f16* ot = (f16*)smem;
  float* dsrc = (float*)(smem + 16384);
  float* ddst = (float*)(smem + 16896);
  float* scf  = (float*)(smem + 17408);   // [128] scale
  float* shf  = scf + 128;                // [128] shift
  float* sst1 = (float*)(smem + 18432);   // [256]
  float* sst2 = sst1 + 256;               // [256]
  int tid = threadIdx.x;
  int bn = blockIdx.x * 64;
  int ln = tid >> 2, qt = tid & 3;
  int w = tid >> 6, lane = tid & 63;
  int q = lane >> 4, l15 = lane & 15;
  int mtb = (w & 1) * 2;
  int ntb = (w >> 1) * 4;
  f16* wp = aS + ln * LPAD + qt * 32;
  if (yres) {
    // in-block GraphNorm stats from psum partials (visible via launch boundary)
    {
      int c = tid & 127, hf = tid >> 7;
      float S = 0.f, Q = 0.f;
      for (int s = hf; s < 128; s += 2) { S += ps[s * 128 + c]; Q += pq[s * 128 + c]; }
      sst1[tid] = S; sst2[tid] = Q;
      __syncthreads();
      if (hf == 0) {
        double Sd = (double)sst1[c] + (double)sst1[c + 128];
        double Qd = (double)sst2[c] + (double)sst2[c + 128];
        double invn = 1.0 / (double)n;
        double mean = Sd * invn;
        double mt = (double)nms[c] * mean;
        double var = Qd * invn - 2.0 * mt * mean + mt * mt;
        float rstd = rsqrtf((float)var + 1e-5f);
        float sc = nw[c] * rstd;
        scf[c] = sc;
        shf[c] = nbb[c] - sc * (float)mt;
      }
      __syncthreads();
    }
    // fused residual: x += lrelu(scale*y + shift); LDS gets f16(x)
    int row = bn + ln;
    if (row < n) {
      const float4* yp = (const float4*)(yres + (size_t)row * 128 + qt * 32);
      float4* xp = (float4*)(xf + (size_t)row * 128 + qt * 32);
      const float4* scp = (const float4*)(scf + qt * 32);
      const float4* shp = (const float4*)(shf + qt * 32);
#pragma unroll
      for (int jj = 0; jj < 8; jj++) {
        float4 yv = yp[jj], xv = xp[jj], sc = scp[jj], sh = shp[jj];
        xv.x += lrelu(sc.x * yv.x + sh.x, 0.01f);
        xv.y += lrelu(sc.y * yv.y + sh.y, 0.01f);
        xv.z += lrelu(sc.z * yv.z + sh.z, 0.01f);
        xv.w += lrelu(sc.w * yv.w + sh.w, 0.01f);
        xp[jj] = xv;
        f16x4 o = { (f16)xv.x, (f16)xv.y, (f16)xv.z, (f16)xv.w };
        *(f16x4*)(wp + jj * 4) = o;
      }
    } else {
      f16x8 z = {};
#pragma unroll
      for (int jj = 0; jj < 4; jj++) *(f16x8*)(wp + jj * 8) = z;
    }
  } else {
    int xrow = bn + ln; if (xrow > n - 1) xrow = n - 1;
    const f16* srcp = XH + (size_t)xrow * 128 + qt * 32;
    *(f16x8*)(wp)      = *(const f16x8*)(srcp);
    *(f16x8*)(wp + 8)  = *(const f16x8*)(srcp + 8);
    *(f16x8*)(wp + 16) = *(const f16x8*)(srcp + 16);
    *(f16x8*)(wp + 24) = *(const f16x8*)(srcp + 24);
  }
  float av[4], bv[4];
  if (asrc) {
#pragma unroll
    for (int ni = 0; ni < 4; ni++) {
      av[ni] = asrc[(ntb + ni) * 16 + l15];
      bv[ni] = adst[(ntb + ni) * 16 + l15];
    }
  }
  f32x4 acc[2][4];
#pragma unroll
  for (int a = 0; a < 2; a++)
#pragma unroll
    for (int b = 0; b < 4; b++) { acc[a][b][0]=0.f; acc[a][b][1]=0.f; acc[a][b][2]=0.f; acc[a][b][3]=0.f; }
  __syncthreads();
#pragma unroll
  for (int kcl = 0; kcl < 4; kcl++) {
    f16x8 a_h[2];
#pragma unroll
    for (int mi = 0; mi < 2; mi++)
      a_h[mi] = *(const f16x8*)(aS + ((mtb + mi) * 16 + l15) * LPAD + kcl * 32 + q * 8);
    int kb = kcl * 4 + q;
#pragma unroll
    for (int ni = 0; ni < 4; ni++) {
      size_t boff = ((size_t)kb * 128 + (ntb + ni) * 16 + l15) * 8;
      f16x8 bh = *(const f16x8*)(wh + boff);
      f16x8 bl = *(const f16x8*)(wl + boff);
#pragma unroll
      for (int mi = 0; mi < 2; mi++) {
        acc[mi][ni] = __builtin_amdgcn_mfma_f32_16x16x32_f16(a_h[mi], bh, acc[mi][ni], 0, 0, 0);
        acc[mi][ni] = __builtin_amdgcn_mfma_f32_16x16x32_f16(a_h[mi], bl, acc[mi][ni], 0, 0, 0);
      }
    }
  }
  __syncthreads();
  if (asrc) {
#pragma unroll
    for (int mi = 0; mi < 2; mi++)
#pragma unroll
      for (int r = 0; r < 4; r++) {
        float ps2 = 0.f, pd = 0.f;
#pragma unroll
        for (int ni = 0; ni < 4; ni++) { ps2 += acc[mi][ni][r] * av[ni]; pd += acc[mi][ni][r] * bv[ni]; }
#pragma unroll
        for (int msk = 8; msk > 0; msk >>= 1) {
          ps2 += __shfl_xor(ps2, msk, 64);
          pd += __shfl_xor(pd, msk, 64);
        }
        if (l15 == 0) {
          int row = (mtb + mi) * 16 + q * 4 + r;
          dsrc[row * 2 + (w >> 1)] = ps2;
          ddst[row * 2 + (w >> 1)] = pd;
        }
      }
  }
#pragma unroll
  for (int mi = 0; mi < 2; mi++)
#pragma unroll
    for (int ni = 0; ni < 4; ni++)
#pragma unroll
      for (int r = 0; r < 4; r++)
        ot[((mtb + mi) * 16 + q * 4 + r) * 128 + (ntb + ni) * 16 + l15] = (f16)acc[mi][ni][r];
  __syncthreads();
  if (bn + ln < n) {
    f16* dst = H16 + (size_t)(bn + ln) * 128 + qt * 32;
    const f16* srcp = ot + ln * 128 + qt * 32;
#pragma unroll
    for (int jj = 0; jj < 4; jj++)
      *(f16x8*)(dst + jj * 8) = *(const f16x8*)(srcp + jj * 8);
  }
  if (asrc && tid < 64 && bn + tid < n) {
    als[bn + tid] = dsrc[tid * 2] + dsrc[tid * 2 + 1];
    ald[bn + tid] = ddst[tid * 2] + ddst[tid * 2 + 1];
  }
}

// ---------------- GCN aggregation: 8-wide gather rounds + fused column stats ----
__global__ __launch_bounds__(256) void k_gcn_agg16(const f16x2* __restrict__ H2,
    const float* __restrict__ dinv, const int* __restrict__ row_ptr,
    const int* __restrict__ csr, const float* __restrict__ csrw,
    const float* __restrict__ bias,
    float2* __restrict__ out2, f16x2* __restrict__ xh_out, int n, int leaky_flag,
    float* __restrict__ psum, float* __restrict__ psumsq) {
  int w = threadIdx.x >> 6;
  int node = blockIdx.x * 4 + w;
  int lane = threadIdx.x & 63;
  __shared__ float s1[4][128], s2[4][128];
  float vx = 0.f, vy = 0.f;
  if (node < n) {
    int rs = row_ptr[node], re = row_ptr[node + 1];
    int d = re - rs;
    float dn = dinv[node];
    int  sidx = (lane < d) ? csr[rs + lane]  : 0;
    float swt = (lane < d) ? csrw[rs + lane] : 0.f;
    f16x2 sv = H2[(size_t)node * 64 + lane];
    float ax = dn * dn * (float)sv[0], ay = dn * dn * (float)sv[1];
    int dl = d < 64 ? d : 64;
    int dl8 = (dl + 7) & ~7;      // padded rounds: 8 independent gathers in flight
    for (int j = 0; j < dl8; j += 8) {
      int ii[8]; float ww[8];
#pragma unroll
      for (int u = 0; u < 8; u++) {
        ii[u] = __shfl(sidx, j + u, 64);
        ww[u] = __shfl(swt,  j + u, 64);
      }
      f16x2 vv[8];
#pragma unroll
      for (int u = 0; u < 8; u++) vv[u] = H2[(size_t)ii[u] * 64 + lane];
#pragma unroll
      for (int u = 0; u < 8; u++) {
        ax += ww[u] * (float)vv[u][0];
        ay += ww[u] * (float)vv[u][1];
      }
    }
    for (int e = rs + 64; e < re; e++) {   // rare deg>64 tail
      int s = csr[e]; float wv = csrw[e];
      f16x2 v = H2[(size_t)s * 64 + lane];
      ax += wv * (float)v[0]; ay += wv * (float)v[1];
    }
    float2 bvv = ((const float2*)bias)[lane];
    vx = ax + bvv.x; vy = ay + bvv.y;
    if (leaky_flag) { vx = lrelu(vx, 0.01f); vy = lrelu(vy, 0.01f); }
    out2[(size_t)node * 64 + lane] = make_float2(vx, vy);
    if (xh_out) { f16x2 o = { (f16)vx, (f16)vy }; xh_out[(size_t)node * 64 + lane] = o; }
  }
  if (psum) {
    s1[w][2*lane] = vx;  s1[w][2*lane+1] = vy;
    s2[w][2*lane] = vx*vx; s2[w][2*lane+1] = vy*vy;
    __syncthreads();
    int t = threadIdx.x;
    if (t < 128) {
      float S = s1[0][t] + s1[1][t] + s1[2][t] + s1[3][t];
      float Q = s2[0][t] + s2[1][t] + s2[2][t] + s2[3][t];
      int slot = blockIdx.x & 127;
      atomicAdd(&psum[slot * 128 + t], S);
      atomicAdd(&psumsq[slot * 128 + t], Q);
    }
  }
}

// ---------------- GAT aggregation: 8-wide gather rounds + fused stats ----------
__global__ __launch_bounds__(256) void k_gat_agg16(const f16x2* __restrict__ H2,
    const float* __restrict__ als, const float* __restrict__ ald,
    const int* __restrict__ row_ptr, const int* __restrict__ csr,
    const float* __restrict__ bias, float2* __restrict__ y2, int n,
    float* __restrict__ psum, float* __restrict__ psumsq) {
  int w = threadIdx.x >> 6;
  int node = blockIdx.x * 4 + w;
  int lane = threadIdx.x & 63;
  __shared__ float s1[4][128], s2[4][128];
  float vx = 0.f, vy = 0.f;
  if (node < n) {
    int rs = row_ptr[node], re = row_ptr[node + 1];
    int d = re - rs;
    float aldn = ald[node];
    float e_self = lrelu(als[node] + aldn, 0.2f);
    f16x2 sv = H2[(size_t)node * 64 + lane];
    float ax, ay, sm;
    if (d <= 64) {
      int sidx = (lane < d) ? csr[rs + lane] : 0;
      float e_k = (lane < d) ? lrelu(als[sidx] + aldn, 0.2f) : -3.4e38f;
      float tmx = e_k;
      for (int off = 1; off < 64; off <<= 1) tmx = fmaxf(tmx, __shfl_xor(tmx, off, 64));
      float mx = fmaxf(e_self, tmx);
      float g_k = (lane < d) ? __expf(e_k - mx) : 0.f;   // pad lanes weight 0
      float tsm = g_k;
      for (int off = 1; off < 64; off <<= 1) tsm += __shfl_xor(tsm, off, 64);
      float ws = __expf(e_self - mx);
      sm = tsm + ws;
      ax = ws * (float)sv[0]; ay = ws * (float)sv[1];
      int d8 = (d + 7) & ~7;     // padded rounds: 8 independent gathers in flight
      for (int j = 0; j < d8; j += 8) {
        int ii[8]; float gg[8];
#pragma unroll
        for (int u = 0; u < 8; u++) {
          ii[u] = __shfl(sidx, j + u, 64);
          gg[u] = __shfl(g_k,  j + u, 64);
        }
        f16x2 vv[8];
#pragma unroll
        for (int u = 0; u < 8; u++) vv[u] = H2[(size_t)ii[u] * 64 + lane];
#pragma unroll
        for (int u = 0; u < 8; u++) {
          ax += gg[u] * (float)vv[u][0];
          ay += gg[u] * (float)vv[u][1];
        }
      }
    } else {  // rare deg>64 slow path
      float mx = e_self;
      for (int i = rs + lane; i < re; i += 64) mx = fmaxf(mx, lrelu(als[csr[i]] + aldn, 0.2f));
      for (int off = 1; off < 64; off <<= 1) mx = fmaxf(mx, __shfl_xor(mx, off, 64));
      float ws = __expf(e_self - mx);
      sm = ws;
      ax = ws * (float)sv[0]; ay = ws * (float)sv[1];
      for (int i = rs; i < re; i++) {
        int s = csr[i];
        float g = __expf(lrelu(als[s] + aldn, 0.2f) - mx);
        f16x2 v = H2[(size_t)s * 64 + lane];
        sm += g; ax += g*(float)v[0]; ay += g*(float)v[1];
      }
    }
    float inv_s = 1.f / sm;
    float2 bvv = ((const float2*)bias)[lane];
    vx = ax * inv_s + bvv.x; vy = ay * inv_s + bvv.y;
    y2[(size_t)node * 64 + lane] = make_float2(vx, vy);
  }
  s1[w][2*lane] = vx;  s1[w][2*lane+1] = vy;
  s2[w][2*lane] = vx*vx; s2[w][2*lane+1] = vy*vy;
  __syncthreads();
  int t = threadIdx.x;
  if (t < 128) {
    float S = s1[0][t] + s1[1][t] + s1[2][t] + s1[3][t];
    float Q = s2[0][t] + s2[1][t] + s2[2][t] + s2[3][t];
    int slot = blockIdx.x & 127;
    atomicAdd(&psum[slot * 128 + t], S);
    atomicAdd(&psumsq[slot * 128 + t], Q);
  }
}

// ---------------- GraphNorm stats (single use: final GAT stats for head) -------
__global__ __launch_bounds__(256) void k_stats(const float* __restrict__ psum,
    const float* __restrict__ psumsq, const float* __restrict__ w,
    const float* __restrict__ bb, const float* __restrict__ ms,
    float* __restrict__ scaleA, float* __restrict__ shiftA, int n) {
  int t = threadIdx.x, c = t & 127, half = t >> 7;
  float S = 0.f, Q = 0.f;
  for (int s = half; s < 128; s += 2) { S += psum[s * 128 + c]; Q += psumsq[s * 128 + c]; }
  __shared__ float sh[256], sq[256];
  sh[t] = S; sq[t] = Q;
  __syncthreads();
  if (half == 0) {
    double Sd = (double)sh[c] + (double)sh[c + 128];
    double Qd = (double)sq[c] + (double)sq[c + 128];
    double invn = 1.0 / (double)n;
    double mean = Sd * invn;
    double mt = (double)ms[c] * mean;
    double var = Qd * invn - 2.0 * mt * mean + mt * mt;
    float rstd = rsqrtf((float)var + 1e-5f);
    float sc = w[c] * rstd;
    scaleA[c] = sc;
    shiftA[c] = bb[c] - sc * (float)mt;
  }
}

// ---------------- Output head: final residual fused into the W_out dot -------
__global__ __launch_bounds__(256) void k_dot1_res(const float* __restrict__ y,
    const float* __restrict__ scA, const float* __restrict__ shA,
    const float* __restrict__ x, const float* __restrict__ wv,
    float* __restrict__ o, int n) {
  int node = blockIdx.x * 4 + (threadIdx.x >> 6);
  int lane = threadIdx.x & 63;
  if (node >= n) return;
  float2 yv = ((const float2*)y)[(size_t)node * 64 + lane];
  float2 xv = ((const float2*)x)[(size_t)node * 64 + lane];
  float2 sc = ((const float2*)scA)[lane];
  float2 sh = ((const float2*)shA)[lane];
  float hx = xv.x + lrelu(sc.x * yv.x + sh.x, 0.01f);
  float hy = xv.y + lrelu(sc.y * yv.y + sh.y, 0.01f);
  float2 v1 = ((const float2*)wv)[lane];
  float s1 = hx * v1.x + hy * v1.y;
  for (int off = 32; off > 0; off >>= 1) s1 += __shfl_down(s1, off, 64);
  if (lane == 0) o[node] = s1;
}

__global__ __launch_bounds__(256) void k_scalar_agg(const float* __restrict__ xsv,
    const float* __restrict__ dinv, const int* __restrict__ row_ptr,
    const int* __restrict__ csr, const float* __restrict__ csrw,
    const float* __restrict__ b_out, float* __restrict__ xout, int n) {
  int i = blockIdx.x * 256 + threadIdx.x;
  if (i >= n) return;
  float dn = dinv[i];
  float acc = dn * dn * xsv[i];
  int re = row_ptr[i + 1];
  for (int e = row_ptr[i]; e < re; e++)
    acc += csrw[e] * xsv[csr[e]];
  xout[i] = lrelu(acc + b_out[0], 0.01f);
}

__global__ __launch_bounds__(256) void k_fc1(const float* __restrict__ xout,
    const float* __restrict__ fw, float* __restrict__ pfc, int n, int chunk) {
  int b = blockIdx.x, t = threadIdx.x;
  int c = t & 127, half = t >> 7;
  int s0 = b * chunk;
  int s1 = s0 + chunk; if (s1 > n) s1 = n;
  float s = 0.f;
  for (int i = s0 + half; i < s1; i += 2) s += xout[i] * fw[(size_t)i * 128 + c];
  __shared__ float sh[256];
  sh[t] = s; __syncthreads();
  if (half == 0) pfc[b * 128 + c] = sh[c] + sh[c + 128];
}

__global__ __launch_bounds__(128) void k_final(const float* __restrict__ pfc,
    const float* __restrict__ b1, const float* __restrict__ fw2,
    const float* __restrict__ b2, float* __restrict__ out) {
  int c = threadIdx.x;
  float s = 0.f;
  for (int b = 0; b < 128; b++) s += pfc[b * 128 + c];
  float hv = lrelu(s + b1[c], 0.01f);
  __shared__ float h1[128];
  h1[c] = hv; __syncthreads();
  float o = b2[c];
  for (int j = 0; j < 128; j++) o += h1[j] * fw2[j * 128 + c];
  out[c] = o;
}

// ---------------- host ----------------
extern "C" void kernel_launch(void* const* d_in, const int* in_sizes, int n_in,
                              void* d_out, int out_size, void* d_ws, size_t ws_size,
                              hipStream_t stream) {
  const int* poi      = (const int*)d_in[0];
  const float* dist   = (const float*)d_in[1];
  const int* ei       = (const int*)d_in[2];
  const float* emb    = (const float*)d_in[3];
  const float* W_in   = (const float*)d_in[4];
  const float* b_in   = (const float*)d_in[5];
  const float* gcn_W  = (const float*)d_in[6];
  const float* gcn_b  = (const float*)d_in[7];
  const float* norm_w = (const float*)d_in[8];
  const float* norm_b = (const float*)d_in[9];
  const float* norm_ms= (const float*)d_in[10];
  const float* gat_W  = (const float*)d_in[11];
  const float* gat_as = (const float*)d_in[12];
  const float* gat_ad = (const float*)d_in[13];
  const float* gat_b  = (const float*)d_in[14];
  const float* W_out  = (const float*)d_in[15];
  const float* b_out  = (const float*)d_in[16];
  const float* fc1_W  = (const float*)d_in[17];
  const float* fc1_b  = (const float*)d_in[18];
  const float* fc2_W  = (const float*)d_in[19];
  const float* fc2_b  = (const float*)d_in[20];

  const int N   = in_sizes[0] / 32;
  const int E   = in_sizes[2] / 2;
  const int POI = in_sizes[3] / 128;
  const int* srcp = ei;
  const int* dstp = ei + E;
  float* out = (float*)d_out;

  char* p = (char*)d_ws;
  auto alloc = [&](size_t bytes) { char* r = p; p += (bytes + 255) & ~(size_t)255; return r; };
  float* x   = (float*)alloc((size_t)N * 128 * 4);
  f16* h16   = (f16*)alloc((size_t)N * 128 * 2);
  f16* xh    = (f16*)alloc((size_t)N * 128 * 2);
  size_t Rneed = (size_t)POI * 128 * 2;
  size_t Ry    = (size_t)N * 128 * 4;
  char* R = alloc(Rneed > Ry ? Rneed : Ry);
  f16* ehalf = (f16*)R;
  float* y   = (float*)R;
  const int KBIN = 4128 / 8;
  f16* wih = (f16*)alloc((size_t)KBIN * 128 * 8 * 2);
  f16* wsh = (f16*)alloc((size_t)8 * 16384 * 2);
  f16* wsl = (f16*)alloc((size_t)8 * 16384 * 2);
  float* dinv   = (float*)alloc((size_t)N * 4);
  float* als    = (float*)alloc((size_t)N * 4);
  float* ald    = (float*)alloc((size_t)N * 4);
  float* xsv    = (float*)alloc((size_t)N * 4);
  float* xout   = (float*)alloc((size_t)N * 4);
  float* statsbuf = (float*)alloc((size_t)32 * 16384 * 4);   // 2 MB
  float* pfc    = (float*)alloc(128 * 128 * 4);
  float* scaleA = (float*)alloc(128 * 4);
  float* shiftA = (float*)alloc(128 * 4);
  int* deg     = (int*)alloc((size_t)N * 2 * 4);
  int* fill    = deg + N;
  int* row_ptr = (int*)alloc(((size_t)N + 1) * 4);
  int* csr     = (int*)alloc((size_t)E * 4);
  float* csrw  = (float*)alloc((size_t)E * 4);
  int* bsum    = (int*)alloc(64 * 4);

  const int chunk = (N + 127) / 128;
  const int gblocks = (N + 63) / 64;
  const int eblocks = (E + 255) / 256;
  const int nwb = (N + 3) / 4;
  const int nb1024 = (N + 1023) / 1024;

  hipMemsetAsync(deg, 0, sizeof(int) * 2 * (size_t)N, stream);
  hipMemsetAsync(statsbuf, 0, (size_t)32 * 16384 * 4, stream);

  // merged prep: deg + emb->f16 + W_in pack + gcn/gat pack (independent work)
  int et4 = POI * 128 / 4;
  const int cbl = (et4 + 255) / 256;
  const int pbl = (KBIN * 128 + 255) / 256;
  k_prep<<<eblocks + cbl + pbl + 64, 256, 0, stream>>>(
      dstp, deg, E, eblocks, emb, ehalf, et4, cbl,
      W_in, wih, KBIN, pbl, gcn_W, gat_W, wsh, wsl);

  k_scan1<<<nb1024, 1024, 0, stream>>>(deg, row_ptr, bsum, dinv, N);
  k_scan2<<<1, 64, 0, stream>>>(bsum, nb1024);
  k_scan3<<<(N + 255) / 256, 256, 0, stream>>>(row_ptr, bsum, N);
  k_fill<<<eblocks, 256, 0, stream>>>(srcp, dstp, row_ptr, dinv, fill, csr, csrw, E);

  // input layer
  k_mfma_embed<<<gblocks, 512, 0, stream>>>(poi, dist, ehalf, wih, h16, N);
  k_gcn_agg16<<<nwb, 256, 0, stream>>>((const f16x2*)h16, dinv, row_ptr, csr, csrw, b_in,
                                       (float2*)x, (f16x2*)xh, N, 1, nullptr, nullptr);

  for (int l = 0; l < 4; l++) {
    const f16* gh = wsh + (size_t)l * 16384;
    const f16* gl = wsl + (size_t)l * 16384;
    const f16* th = wsh + (size_t)(4 + l) * 16384;
    const f16* tl = wsl + (size_t)(4 + l) * 16384;
    float* ps0 = statsbuf + (size_t)(4 * l) * 16384;   // gcn psum (layer l)
    float* pq0 = ps0 + 16384;
    float* ps1 = ps0 + 2 * 16384;                      // gat psum (layer l)
    float* pq1 = ps0 + 3 * 16384;
    // GCN sub-unit: lin consumes previous-layer GAT stats (residual) for l>0
    if (l == 0)
      k_mfma_lin<<<gblocks, 256, 0, stream>>>(xh, gh, gl, h16, N,
          nullptr, nullptr, nullptr, nullptr,
          nullptr, nullptr, nullptr, nullptr, nullptr, nullptr, nullptr);
    else {
      float* ps1p = statsbuf + (size_t)(4 * (l - 1) + 2) * 16384;
      float* pq1p = ps1p + 16384;
      k_mfma_lin<<<gblocks, 256, 0, stream>>>(nullptr, gh, gl, h16, N,
          nullptr, nullptr, nullptr, nullptr,
          y, ps1p, pq1p, norm_w + (l - 1) * 128, norm_b + (l - 1) * 128,
          norm_ms + (l - 1) * 128, x);
    }
    k_gcn_agg16<<<nwb, 256, 0, stream>>>((const f16x2*)h16, dinv, row_ptr, csr, csrw,
                                         gcn_b + l * 128, (float2*)y, (f16x2*)nullptr, N, 0,
                                         ps0, pq0);
    // GAT sub-unit: lin consumes this layer's GCN stats (residual); a-dot fused
    k_mfma_lin<<<gblocks, 256, 0, stream>>>(nullptr, th, tl, h16, N,
        gat_as + l * 128, gat_ad + l * 128, als, ald,
        y, ps0, pq0, norm_w + l * 128, norm_b + l * 128, norm_ms + l * 128, x);
    k_gat_agg16<<<nwb, 256, 0, stream>>>((const f16x2*)h16, als, ald, row_ptr, csr,
                                         gat_b + l * 128, (float2*)y, N, ps1, pq1);
  }

  // output head: single k_stats for the final GAT norm, then fused dot
  {
    float* ps1 = statsbuf + (size_t)(4 * 3 + 2) * 16384;
    float* pq1 = ps1 + 16384;
    k_stats<<<1, 256, 0, stream>>>(ps1, pq1, norm_w + 3 * 128, norm_b + 3 * 128,
                                   norm_ms + 3 * 128, scaleA, shiftA, N);
  }
  k_dot1_res<<<nwb, 256, 0, stream>>>(y, scaleA, shiftA, x, W_out, xsv, N);
  k_scalar_agg<<<(N + 255) / 256, 256, 0, stream>>>(xsv, dinv, row_ptr, csr, csrw, b_out, xout, N);
  k_fc1<<<128, 256, 0, stream>>>(xout, fc1_W, pfc, N, chunk);
  k_final<<<1, 128, 0, stream>>>(pfc, fc1_b, fc2_W, fc2_b, out);
}